// Round 4
// baseline (420.305 us; speedup 1.0000x reference)
//
#include <hip/hip_runtime.h>
#include <stdint.h>

// Block_32521492365607: pre-LN(T-axis) attention block, MI355X gfx950.
// Round 4: BT-GEMM rebuilt as 3-buffer 2-deep pipeline (counted vmcnt(4),
// one barrier/K-step, never drain in-loop) + both-sides LDS column swizzle
// (kb ^= (row>>1)&3) -> 2-way-free bank pattern. FF2 split-K=4.
//
// WS layout (bytes):
//   0: BkT 2MB | 2MB: WvT 2MB | 4MB: WpB 2MB | 6MB: W1B 8MB | 14MB: W2B 8MB
//   22MB: hB 8MB | 30MB: qk 8MB | 38MB: Vt 8MB | 46MB: ctx 8MB
//   (ff1 bf16 [4096,4096] overlays 30..62MB after qk/Vt/ctx are dead)
//   62MB: x2 f32 16MB | 78MB: ln stats. Total ~78.3MB.

#define BDIM 256

typedef __attribute__((ext_vector_type(8))) __bf16 bf16x8;
typedef __attribute__((ext_vector_type(4))) float f32x4;

__device__ __forceinline__ unsigned short f2bf(float f) {
    unsigned u = __float_as_uint(f);
    u += 0x7fff + ((u >> 16) & 1);   // RNE
    return (unsigned short)(u >> 16);
}

__device__ __forceinline__ void gload_lds16(const void* g, void* l) {
    __builtin_amdgcn_global_load_lds(
        (const __attribute__((address_space(1))) void*)g,
        (__attribute__((address_space(3))) void*)l, 16, 0, 0);
}

// ---------------- weight prep ----------------
__global__ void k_cast_bf16(const float* __restrict__ in, unsigned short* __restrict__ out, int n4) {
    int i = blockIdx.x * BDIM + threadIdx.x;
    if (i >= n4) return;
    float4 v = ((const float4*)in)[i];
    ushort4 o;
    o.x = f2bf(v.x); o.y = f2bf(v.y); o.z = f2bf(v.z); o.w = f2bf(v.w);
    ((ushort4*)out)[i] = o;
}

// W[h][c][d] (16,1024,64) -> out[(h*64+d)*1024 + c] bf16, LDS transpose tile.
__global__ void k_headT(const float* __restrict__ W, unsigned short* __restrict__ out) {
    __shared__ float tile[64][65];
    const int tid = threadIdx.x;
    const int c0 = blockIdx.x * 64, h = blockIdx.y;
    const float* src = W + ((long)h << 16) + (long)c0 * 64;
    #pragma unroll
    for (int j = 0; j < 16; ++j) {
        int idx = j * 256 + tid;
        tile[idx >> 6][idx & 63] = src[idx];   // coalesced over d
    }
    __syncthreads();
    #pragma unroll
    for (int j = 0; j < 16; ++j) {
        int idx = j * 256 + tid;
        int d = idx >> 6, c = idx & 63;
        out[(long)(h * 64 + d) * 1024 + c0 + c] = f2bf(tile[c][d]);  // coalesced over c
    }
}

// ---------------- LayerNorm over T axis ----------------
__global__ void k_ln_part(const float* __restrict__ x, float* __restrict__ psum, float* __restrict__ psq) {
    int c = blockIdx.x * BDIM + threadIdx.x;
    int tc = blockIdx.y, b = blockIdx.z;
    const float* p = x + ((long)b << 20) + ((long)tc * 128) * 1024 + c;
    float s = 0.f, ss = 0.f;
    for (int t = 0; t < 128; ++t) {
        float v = p[t * 1024];
        s += v; ss += v * v;
    }
    int o = (b * 8 + tc) * 1024 + c;
    psum[o] = s; psq[o] = ss;
}

__global__ void k_ln_fin(const float* __restrict__ psum, const float* __restrict__ psq,
                         float* __restrict__ mean, float* __restrict__ rstd) {
    int i = blockIdx.x * BDIM + threadIdx.x;  // 4096 = B*C
    int b = i >> 10, c = i & 1023;
    float s = 0.f, ss = 0.f;
    for (int j = 0; j < 8; ++j) {
        s  += psum[(b * 8 + j) * 1024 + c];
        ss += psq[(b * 8 + j) * 1024 + c];
    }
    float m = s * (1.0f / 1024.0f);
    float var = (ss - 1024.0f * m * m) * (1.0f / 1023.0f);   // ddof=1
    mean[i] = m;
    rstd[i] = rsqrtf(var + 1e-5f);
}

__global__ void k_ln_apply(const float* __restrict__ x, const float* __restrict__ mean,
                           const float* __restrict__ rstd, const float* __restrict__ g,
                           const float* __restrict__ beta, unsigned short* __restrict__ out) {
    int i = blockIdx.x * BDIM + threadIdx.x;   // 1M, 4 elems each
    int flat = i << 2;
    int b = flat >> 20, c = flat & 1023;
    float4 xv = ((const float4*)x)[i];
    float4 mv = *(const float4*)&mean[(b << 10) + c];
    float4 rv = *(const float4*)&rstd[(b << 10) + c];
    float4 gv = *(const float4*)&g[c];
    float4 bv = *(const float4*)&beta[c];
    ushort4 o;
    o.x = f2bf(gv.x * (xv.x - mv.x) * rv.x + bv.x);
    o.y = f2bf(gv.y * (xv.y - mv.y) * rv.y + bv.y);
    o.z = f2bf(gv.z * (xv.z - mv.z) * rv.z + bv.z);
    o.w = f2bf(gv.w * (xv.w - mv.w) * rv.w + bv.w);
    ((ushort4*)out)[i] = o;
}

// prefill for split-K FF2: out[i] = res[i] + bias[col]
__global__ void k_addbias(const float* __restrict__ res, const float* __restrict__ bias,
                          float* __restrict__ out) {
    int i = blockIdx.x * BDIM + threadIdx.x;   // 1M float4
    int c = (i << 2) & 1023;
    float4 r = ((const float4*)res)[i];
    float4 bv = *(const float4*)&bias[c];
    r.x += bv.x; r.y += bv.y; r.z += bv.z; r.w += bv.w;
    ((float4*)out)[i] = r;
}

// ---------------- BT GEMM: C[i,j] = sum_k A[i,k]*B[j,k] ----------------
// 3-buffer 2-deep pipeline: one barrier/K-step, s_waitcnt vmcnt(4) (counted,
// never 0 in-loop). LDS tile [128][4 x 16B] with kb ^= (row>>1)&3 swizzle,
// applied on the global SOURCE column (linear LDS dest, rule both-sides).
// EPI: 0 = bf16 out; 1 = f32 out + bias[col] + res; 2 = bf16 relu(v+bias);
//      3 = f32 atomicAdd into C (split-K).
template <int EPI>
__global__ __launch_bounds__(256, 3) void k_gemm_bt(
    const unsigned short* __restrict__ A, const unsigned short* __restrict__ B,
    void* __restrict__ Cv, const float* __restrict__ bias, const float* __restrict__ res,
    int N, int K, int ldA, int ldB, long sA, long sB, long sC)
{
    __shared__ __align__(16) unsigned short As[3][128 * 32];
    __shared__ __align__(16) unsigned short Bs[3][128 * 32];
    const int tid = threadIdx.x;
    const int wave = tid >> 6, lane = tid & 63;
    const long bz = blockIdx.z;
    const int m0 = blockIdx.y * 128, n0 = blockIdx.x * 128;

    // staging: wave w covers rows w*16..+15 (and +64); lane>>2 = row, lane&3 = kb.
    // source column pre-swizzled so linear LDS slot (row,kb) holds data kb^f(row).
    const int srow = wave * 16 + (lane >> 2);
    const int kbs = (lane & 3) ^ ((srow >> 1) & 3);
    const unsigned short* gA0 = A + bz * sA + (long)(m0 + srow) * ldA + kbs * 8;
    const unsigned short* gB0 = B + bz * sB + (long)(n0 + srow) * ldB + kbs * 8;
    const long rowoffA = (long)64 * ldA;
    const long rowoffB = (long)64 * ldB;
    const int lofs = wave * 512;   // u16 units; 1KB per wave per issue

    f32x4 acc[4][4] = {};
    const int wm = (wave >> 1) * 64, wn = (wave & 1) * 64;
    const int lr = lane & 15, lg = lane >> 4;
    // read column block, same XOR: f(row) = (row>>1)&3 reduces to (lr>>1)&3
    const int aoff = (lg ^ ((lr >> 1) & 3)) * 8;

    const int nsteps = K >> 5;

    auto stage = [&](int step, int buf) {
        const long ko = (long)step * 32;
        unsigned short* a = &As[buf][lofs];
        unsigned short* b = &Bs[buf][lofs];
        gload_lds16(gA0 + ko, a);
        gload_lds16(gA0 + rowoffA + ko, a + 2048);
        gload_lds16(gB0 + ko, b);
        gload_lds16(gB0 + rowoffB + ko, b + 2048);
    };

    stage(0, 0);
    stage(1, 1);

    int cur = 0;
    for (int t = 0; t < nsteps; ++t) {
        if (t + 1 < nsteps) {
            asm volatile("s_waitcnt vmcnt(4)" ::: "memory");   // tile t landed; t+1 in flight
        } else {
            asm volatile("s_waitcnt vmcnt(0)" ::: "memory");   // final tile
        }
        __builtin_amdgcn_s_barrier();
        __builtin_amdgcn_sched_barrier(0);
        if (t + 2 < nsteps) {
            int pbuf = cur + 2; if (pbuf >= 3) pbuf -= 3;
            stage(t + 2, pbuf);   // overwrites buf of tile t-1 (reads retired pre-barrier)
        }
        bf16x8 af[4], bfr[4];
        #pragma unroll
        for (int i = 0; i < 4; ++i) {
            af[i]  = *(const bf16x8*)&As[cur][(wm + i * 16 + lr) * 32 + aoff];
            bfr[i] = *(const bf16x8*)&Bs[cur][(wn + i * 16 + lr) * 32 + aoff];
        }
        #pragma unroll
        for (int i = 0; i < 4; ++i)
            #pragma unroll
            for (int j = 0; j < 4; ++j)
                acc[i][j] = __builtin_amdgcn_mfma_f32_16x16x32_bf16(af[i], bfr[j], acc[i][j], 0, 0, 0);
        __builtin_amdgcn_sched_barrier(0);   // pin MFMAs (ds_read consumers) before next wait
        cur = cur + 1; if (cur == 3) cur = 0;
    }

    const int cr0 = lg * 4;
    #pragma unroll
    for (int mi = 0; mi < 4; ++mi) {
        #pragma unroll
        for (int r = 0; r < 4; ++r) {
            const int row = m0 + wm + mi * 16 + cr0 + r;
            const long rb = bz * sC + (long)row * N;
            #pragma unroll
            for (int nj = 0; nj < 4; ++nj) {
                const int col = n0 + wn + nj * 16 + lr;
                float v = acc[mi][nj][r];
                if (EPI == 0) {
                    ((unsigned short*)Cv)[rb + col] = f2bf(v);
                } else if (EPI == 1) {
                    ((float*)Cv)[rb + col] = v + bias[col] + res[rb + col];
                } else if (EPI == 2) {
                    v += bias[col];
                    ((unsigned short*)Cv)[rb + col] = f2bf(v > 0.f ? v : 0.f);
                } else {
                    atomicAdd(&((float*)Cv)[rb + col], v);
                }
            }
        }
    }
}

// ---------------- flash attention (causal, q==k tensor) ----------------
#define CEXP 0.18033688f   // 0.125 * log2(e)
#define PSTRIDE 72

__global__ __launch_bounds__(256, 2) void k_attn(
    const unsigned short* __restrict__ qk, const unsigned short* __restrict__ vt,
    unsigned short* __restrict__ ctx)
{
    __shared__ __align__(16) unsigned short Ks[64 * 64];
    __shared__ __align__(16) unsigned short Vs[64 * 64];
    __shared__ __align__(16) unsigned short P[4][16 * PSTRIDE];
    const int tid = threadIdx.x;
    const int wave = tid >> 6, lane = tid & 63;
    const int bh = blockIdx.x >> 3, pairIdx = blockIdx.x & 7;
    const int b = bh >> 4, h = bh & 15;
    const int lr = lane & 15, lg = lane >> 4;

    const int swz = (lr & 7) << 4;
    const int cby0 = (lg * 16) ^ swz;
    const int cby1 = (64 + lg * 16) ^ swz;
    const int srow_l = lane >> 3;
    const int scol = ((lane & 7) * 8) ^ (srow_l << 3);   // u16 units

    unsigned short* Pw = P[wave];
    char* KsB = (char*)Ks;
    char* VsB = (char*)Vs;
    const unsigned short* qbase = qk + ((long)b << 20) + h * 64;
    const unsigned short* vb    = vt + ((long)(b * 16 + h) << 16);

    #pragma unroll 1
    for (int phase = 0; phase < 2; ++phase) {
        const int qb = phase ? (15 - pairIdx) : pairIdx;
        const int q0 = qb << 6;
        const int qw = q0 + wave * 16;

        const unsigned short* qrow = qbase + (long)(qw + lr) * 1024 + lg * 8;
        const bf16x8 aq0 = *(const bf16x8*)qrow;
        const bf16x8 aq1 = *(const bf16x8*)(qrow + 32);

        f32x4 acc[4] = {};
        float mrow[4] = {-1e30f, -1e30f, -1e30f, -1e30f};
        float lrow[4] = {0.f, 0.f, 0.f, 0.f};

        for (int c = 0; c <= qb; ++c) {
            const int k0 = c << 6;
            __syncthreads();
            #pragma unroll
            for (int i = 0; i < 2; ++i) {
                const int row = i * 32 + wave * 8 + srow_l;
                gload_lds16(qbase + (long)(k0 + row) * 1024 + scol,
                            KsB + i * 4096 + wave * 1024);
                gload_lds16(vb + (long)row * 1024 + k0 + scol,
                            VsB + i * 4096 + wave * 1024);
            }
            __syncthreads();

            f32x4 s[4];
            #pragma unroll
            for (int t = 0; t < 4; ++t) {
                const int r = t * 16 + lr;
                bf16x8 bk0 = *(const bf16x8*)(KsB + r * 128 + cby0);
                bf16x8 bk1 = *(const bf16x8*)(KsB + r * 128 + cby1);
                f32x4 z = {};
                z = __builtin_amdgcn_mfma_f32_16x16x32_bf16(aq0, bk0, z, 0, 0, 0);
                s[t] = __builtin_amdgcn_mfma_f32_16x16x32_bf16(aq1, bk1, z, 0, 0, 0);
            }
            if (c == qb) {
                #pragma unroll
                for (int t = 0; t < 4; ++t) {
                    const int col = t * 16 + lr;
                    #pragma unroll
                    for (int r = 0; r < 4; ++r)
                        if (col > wave * 16 + lg * 4 + r) s[t][r] = -1e30f;
                }
            }
            float fac[4];
            #pragma unroll
            for (int r = 0; r < 4; ++r) {
                float v = fmaxf(fmaxf(s[0][r], s[1][r]), fmaxf(s[2][r], s[3][r]));
                v = fmaxf(v, __shfl_xor(v, 1));
                v = fmaxf(v, __shfl_xor(v, 2));
                v = fmaxf(v, __shfl_xor(v, 4));
                v = fmaxf(v, __shfl_xor(v, 8));
                float mn = fmaxf(mrow[r], v);
                fac[r] = exp2f((mrow[r] - mn) * CEXP);
                mrow[r] = mn;
            }
            float psum[4] = {0.f, 0.f, 0.f, 0.f};
            #pragma unroll
            for (int t = 0; t < 4; ++t) {
                #pragma unroll
                for (int r = 0; r < 4; ++r) {
                    float p = exp2f((s[t][r] - mrow[r]) * CEXP);
                    psum[r] += p;
                    Pw[(lg * 4 + r) * PSTRIDE + t * 16 + lr] = f2bf(p);
                }
            }
            #pragma unroll
            for (int r = 0; r < 4; ++r) {
                float v = psum[r];
                v += __shfl_xor(v, 1); v += __shfl_xor(v, 2);
                v += __shfl_xor(v, 4); v += __shfl_xor(v, 8);
                lrow[r] = lrow[r] * fac[r] + v;
            }
            #pragma unroll
            for (int ni = 0; ni < 4; ++ni)
                #pragma unroll
                for (int r = 0; r < 4; ++r)
                    acc[ni][r] *= fac[r];
            const bf16x8 pa0 = *(const bf16x8*)&Pw[lr * PSTRIDE + lg * 8];
            const bf16x8 pa1 = *(const bf16x8*)&Pw[lr * PSTRIDE + 32 + lg * 8];
            #pragma unroll
            for (int ni = 0; ni < 4; ++ni) {
                const int vr = ni * 16 + lr;
                bf16x8 bv0 = *(const bf16x8*)(VsB + vr * 128 + cby0);
                bf16x8 bv1 = *(const bf16x8*)(VsB + vr * 128 + cby1);
                acc[ni] = __builtin_amdgcn_mfma_f32_16x16x32_bf16(pa0, bv0, acc[ni], 0, 0, 0);
                acc[ni] = __builtin_amdgcn_mfma_f32_16x16x32_bf16(pa1, bv1, acc[ni], 0, 0, 0);
            }
        }

        unsigned short* crow = ctx + ((long)(b * 1024 + qw)) * 1024 + h * 64;
        #pragma unroll
        for (int r = 0; r < 4; ++r) {
            const float inv = 1.0f / lrow[r];
            #pragma unroll
            for (int ni = 0; ni < 4; ++ni)
                crow[(long)(lg * 4 + r) * 1024 + ni * 16 + lr] = f2bf(acc[ni][r] * inv);
        }
    }
}

// ---------------- launcher ----------------
extern "C" void kernel_launch(void* const* d_in, const int* in_sizes, int n_in,
                              void* d_out, int out_size, void* d_ws, size_t ws_size,
                              hipStream_t stream)
{
    const float* x   = (const float*)d_in[0];
    const float* Wk  = (const float*)d_in[1];
    const float* Wv  = (const float*)d_in[2];
    const float* Wp  = (const float*)d_in[3];
    const float* bp  = (const float*)d_in[4];
    const float* W1  = (const float*)d_in[5];
    const float* b1  = (const float*)d_in[6];
    const float* W2  = (const float*)d_in[7];
    const float* b2  = (const float*)d_in[8];
    const float* g1  = (const float*)d_in[9];
    const float* be1 = (const float*)d_in[10];
    const float* g2  = (const float*)d_in[11];
    const float* be2 = (const float*)d_in[12];
    float* out = (float*)d_out;

    char* ws = (char*)d_ws;
    const long MB = 1024 * 1024;
    unsigned short* BkT = (unsigned short*)(ws);
    unsigned short* WvT = (unsigned short*)(ws + 2 * MB);
    unsigned short* WpB = (unsigned short*)(ws + 4 * MB);
    unsigned short* W1B = (unsigned short*)(ws + 6 * MB);
    unsigned short* W2B = (unsigned short*)(ws + 14 * MB);
    unsigned short* hB  = (unsigned short*)(ws + 22 * MB);
    unsigned short* qkB = (unsigned short*)(ws + 30 * MB);
    unsigned short* VtB = (unsigned short*)(ws + 38 * MB);
    unsigned short* ctx = (unsigned short*)(ws + 46 * MB);
    unsigned short* ff1 = (unsigned short*)(ws + 30 * MB);  // overlays qk/Vt/ctx
    float* x2   = (float*)(ws + 62 * MB);
    float* psum = (float*)(ws + 78 * MB);
    float* psq  = (float*)(ws + 78 * MB + 128 * 1024);
    float* mean = (float*)(ws + 78 * MB + 256 * 1024);
    float* rstd = (float*)(ws + 78 * MB + 272 * 1024);

    // weight prep
    k_cast_bf16<<<1024, BDIM, 0, stream>>>(Wp, WpB, 262144);
    k_cast_bf16<<<4096, BDIM, 0, stream>>>(W1, W1B, 1048576);
    k_cast_bf16<<<4096, BDIM, 0, stream>>>(W2, W2B, 1048576);
    k_headT<<<dim3(16, 16), BDIM, 0, stream>>>(Wk, BkT);
    k_headT<<<dim3(16, 16), BDIM, 0, stream>>>(Wv, WvT);

    // LN1 (over T axis)
    k_ln_part<<<dim3(4, 8, 4), BDIM, 0, stream>>>(x, psum, psq);
    k_ln_fin<<<16, BDIM, 0, stream>>>(psum, psq, mean, rstd);
    k_ln_apply<<<4096, BDIM, 0, stream>>>(x, mean, rstd, g1, be1, hB);

    // projections
    k_gemm_bt<0><<<dim3(8, 32, 1), BDIM, 0, stream>>>(hB, BkT, qkB, nullptr, nullptr, 1024, 1024, 1024, 1024, 0, 0, 0);
    k_gemm_bt<0><<<dim3(8, 8, 4), BDIM, 0, stream>>>(WvT, hB, VtB, nullptr, nullptr, 1024, 1024, 1024, 1024, 0, MB, MB);

    // flash attention -> ctx bf16 [4096, 1024]
    k_attn<<<512, BDIM, 0, stream>>>(qkB, VtB, ctx);

    // out-proj + bias + residual -> x2 f32
    k_gemm_bt<1><<<dim3(8, 32, 1), BDIM, 0, stream>>>(ctx, WpB, x2, bp, x, 1024, 1024, 1024, 1024, 0, 0, 0);

    // LN2
    k_ln_part<<<dim3(4, 8, 4), BDIM, 0, stream>>>(x2, psum, psq);
    k_ln_fin<<<16, BDIM, 0, stream>>>(psum, psq, mean, rstd);
    k_ln_apply<<<4096, BDIM, 0, stream>>>(x2, mean, rstd, g2, be2, hB);

    // FF1: ff1 = relu(h2 @ W1^T + b1) bf16
    k_gemm_bt<2><<<dim3(32, 32, 1), BDIM, 0, stream>>>(hB, W1B, ff1, b1, nullptr, 4096, 1024, 1024, 1024, 0, 0, 0);

    // FF2 split-K=4: out = x2 + b2 (prefill), then out += ff1 @ W2^T via atomics
    k_addbias<<<4096, BDIM, 0, stream>>>(x2, b2, out);
    k_gemm_bt<3><<<dim3(8, 32, 4), BDIM, 0, stream>>>(ff1, W2B, out, nullptr, nullptr, 1024, 1024, 4096, 4096, 1024, 1024, 0);
}

// Round 5
// 403.012 us; speedup vs baseline: 1.0429x; 1.0429x over previous
//
#include <hip/hip_runtime.h>
#include <stdint.h>

// Block_32521492365607: pre-LN(T-axis) attention block, MI355X gfx950.
// Round 5: new 256x256/BK64/8-wave GEMM (1 barrier + 1 vmcnt(0) per K-tile,
// full-tile prefetch cover, swizzled conflict-free LDS) for FF1 + FF2(splitK4).
// 128x128 GEMM reverted to round-3 loop (kept swizzle). Attention unchanged.
//
// WS layout (bytes):
//   0: BkT 2MB | 2MB: WvT 2MB | 4MB: WpB 2MB | 6MB: W1B 8MB | 14MB: W2B 8MB
//   22MB: hB 8MB | 30MB: qk 8MB | 38MB: Vt 8MB | 46MB: ctx 8MB
//   (ff1 bf16 [4096,4096] overlays 30..62MB after qk/Vt/ctx are dead)
//   62MB: x2 f32 16MB | 78MB: ln stats. Total ~78.3MB.

#define BDIM 256

typedef __attribute__((ext_vector_type(8))) __bf16 bf16x8;
typedef __attribute__((ext_vector_type(4))) float f32x4;

__device__ __forceinline__ unsigned short f2bf(float f) {
    unsigned u = __float_as_uint(f);
    u += 0x7fff + ((u >> 16) & 1);   // RNE
    return (unsigned short)(u >> 16);
}

__device__ __forceinline__ void gload_lds16(const void* g, void* l) {
    __builtin_amdgcn_global_load_lds(
        (const __attribute__((address_space(1))) void*)g,
        (__attribute__((address_space(3))) void*)l, 16, 0, 0);
}

// ---------------- weight prep ----------------
__global__ void k_cast_bf16(const float* __restrict__ in, unsigned short* __restrict__ out, int n4) {
    int i = blockIdx.x * BDIM + threadIdx.x;
    if (i >= n4) return;
    float4 v = ((const float4*)in)[i];
    ushort4 o;
    o.x = f2bf(v.x); o.y = f2bf(v.y); o.z = f2bf(v.z); o.w = f2bf(v.w);
    ((ushort4*)out)[i] = o;
}

// W[h][c][d] (16,1024,64) -> out[(h*64+d)*1024 + c] bf16, LDS transpose tile.
__global__ void k_headT(const float* __restrict__ W, unsigned short* __restrict__ out) {
    __shared__ float tile[64][65];
    const int tid = threadIdx.x;
    const int c0 = blockIdx.x * 64, h = blockIdx.y;
    const float* src = W + ((long)h << 16) + (long)c0 * 64;
    #pragma unroll
    for (int j = 0; j < 16; ++j) {
        int idx = j * 256 + tid;
        tile[idx >> 6][idx & 63] = src[idx];
    }
    __syncthreads();
    #pragma unroll
    for (int j = 0; j < 16; ++j) {
        int idx = j * 256 + tid;
        int d = idx >> 6, c = idx & 63;
        out[(long)(h * 64 + d) * 1024 + c0 + c] = f2bf(tile[c][d]);
    }
}

// ---------------- LayerNorm over T axis ----------------
__global__ void k_ln_part(const float* __restrict__ x, float* __restrict__ psum, float* __restrict__ psq) {
    int c = blockIdx.x * BDIM + threadIdx.x;
    int tc = blockIdx.y, b = blockIdx.z;
    const float* p = x + ((long)b << 20) + ((long)tc * 128) * 1024 + c;
    float s = 0.f, ss = 0.f;
    for (int t = 0; t < 128; ++t) {
        float v = p[t * 1024];
        s += v; ss += v * v;
    }
    int o = (b * 8 + tc) * 1024 + c;
    psum[o] = s; psq[o] = ss;
}

__global__ void k_ln_fin(const float* __restrict__ psum, const float* __restrict__ psq,
                         float* __restrict__ mean, float* __restrict__ rstd) {
    int i = blockIdx.x * BDIM + threadIdx.x;  // 4096 = B*C
    int b = i >> 10, c = i & 1023;
    float s = 0.f, ss = 0.f;
    for (int j = 0; j < 8; ++j) {
        s  += psum[(b * 8 + j) * 1024 + c];
        ss += psq[(b * 8 + j) * 1024 + c];
    }
    float m = s * (1.0f / 1024.0f);
    float var = (ss - 1024.0f * m * m) * (1.0f / 1023.0f);   // ddof=1
    mean[i] = m;
    rstd[i] = rsqrtf(var + 1e-5f);
}

__global__ void k_ln_apply(const float* __restrict__ x, const float* __restrict__ mean,
                           const float* __restrict__ rstd, const float* __restrict__ g,
                           const float* __restrict__ beta, unsigned short* __restrict__ out) {
    int i = blockIdx.x * BDIM + threadIdx.x;   // 1M, 4 elems each
    int flat = i << 2;
    int b = flat >> 20, c = flat & 1023;
    float4 xv = ((const float4*)x)[i];
    float4 mv = *(const float4*)&mean[(b << 10) + c];
    float4 rv = *(const float4*)&rstd[(b << 10) + c];
    float4 gv = *(const float4*)&g[c];
    float4 bv = *(const float4*)&beta[c];
    ushort4 o;
    o.x = f2bf(gv.x * (xv.x - mv.x) * rv.x + bv.x);
    o.y = f2bf(gv.y * (xv.y - mv.y) * rv.y + bv.y);
    o.z = f2bf(gv.z * (xv.z - mv.z) * rv.z + bv.z);
    o.w = f2bf(gv.w * (xv.w - mv.w) * rv.w + bv.w);
    ((ushort4*)out)[i] = o;
}

// prefill for split-K FF2: out[i] = res[i] + bias[col]
__global__ void k_addbias(const float* __restrict__ res, const float* __restrict__ bias,
                          float* __restrict__ out) {
    int i = blockIdx.x * BDIM + threadIdx.x;   // 1M float4
    int c = (i << 2) & 1023;
    float4 r = ((const float4*)res)[i];
    float4 bv = *(const float4*)&bias[c];
    r.x += bv.x; r.y += bv.y; r.z += bv.z; r.w += bv.w;
    ((float4*)out)[i] = r;
}

// ---------------- 128x128 BT GEMM (round-3 loop + swizzle) ----------------
// EPI: 0 = bf16 out; 1 = f32 out + bias[col] + res; 2 = bf16 relu(v+bias)
template <int EPI>
__global__ __launch_bounds__(256, 3) void k_gemm_bt(
    const unsigned short* __restrict__ A, const unsigned short* __restrict__ B,
    void* __restrict__ Cv, const float* __restrict__ bias, const float* __restrict__ res,
    int N, int K, int ldA, int ldB, long sA, long sB, long sC)
{
    __shared__ __align__(16) unsigned short As[2][128 * 32];
    __shared__ __align__(16) unsigned short Bs[2][128 * 32];
    const int tid = threadIdx.x;
    const int wave = tid >> 6, lane = tid & 63;
    const long bz = blockIdx.z;
    const int m0 = blockIdx.y * 128, n0 = blockIdx.x * 128;

    // staging: lane-linear dest; source column pre-swizzled kb^((row>>1)&3)
    const int srow = wave * 16 + (lane >> 2);
    const int kbs = (lane & 3) ^ ((srow >> 1) & 3);
    const unsigned short* gA0 = A + bz * sA + (long)(m0 + srow) * ldA + kbs * 8;
    const unsigned short* gB0 = B + bz * sB + (long)(n0 + srow) * ldB + kbs * 8;
    const long rowoffA = (long)64 * ldA;
    const long rowoffB = (long)64 * ldB;
    const int lofs = wave * 512;

    f32x4 acc[4][4] = {};
    const int wm = (wave >> 1) * 64, wn = (wave & 1) * 64;
    const int lr = lane & 15, lg = lane >> 4;
    const int aoff = (lg ^ ((lr >> 1) & 3)) * 8;   // read undoes the swizzle

    auto stage = [&](int kt, int buf) {
        gload_lds16(gA0 + kt, &As[buf][lofs]);
        gload_lds16(gA0 + rowoffA + kt, &As[buf][2048 + lofs]);
        gload_lds16(gB0 + kt, &Bs[buf][lofs]);
        gload_lds16(gB0 + rowoffB + kt, &Bs[buf][2048 + lofs]);
    };

    stage(0, 0);
    asm volatile("s_waitcnt vmcnt(0)" ::: "memory");
    __builtin_amdgcn_s_barrier();
    __builtin_amdgcn_sched_barrier(0);

    int cur = 0;
    for (int kt = 0; kt < K; kt += 32) {
        const int nxt = cur ^ 1;
        if (kt + 32 < K) stage(kt + 32, nxt);
        bf16x8 af[4], bfr[4];
        #pragma unroll
        for (int i = 0; i < 4; ++i) {
            af[i]  = *(const bf16x8*)&As[cur][(wm + i * 16 + lr) * 32 + aoff];
            bfr[i] = *(const bf16x8*)&Bs[cur][(wn + i * 16 + lr) * 32 + aoff];
        }
        #pragma unroll
        for (int i = 0; i < 4; ++i)
            #pragma unroll
            for (int j = 0; j < 4; ++j)
                acc[i][j] = __builtin_amdgcn_mfma_f32_16x16x32_bf16(af[i], bfr[j], acc[i][j], 0, 0, 0);
        asm volatile("s_waitcnt vmcnt(0)" ::: "memory");
        __builtin_amdgcn_s_barrier();
        __builtin_amdgcn_sched_barrier(0);
        cur = nxt;
    }

    const int cr0 = lg * 4;
    #pragma unroll
    for (int mi = 0; mi < 4; ++mi) {
        #pragma unroll
        for (int r = 0; r < 4; ++r) {
            const int row = m0 + wm + mi * 16 + cr0 + r;
            const long rb = bz * sC + (long)row * N;
            #pragma unroll
            for (int nj = 0; nj < 4; ++nj) {
                const int col = n0 + wn + nj * 16 + lr;
                float v = acc[mi][nj][r];
                if (EPI == 0) {
                    ((unsigned short*)Cv)[rb + col] = f2bf(v);
                } else if (EPI == 1) {
                    ((float*)Cv)[rb + col] = v + bias[col] + res[rb + col];
                } else {
                    v += bias[col];
                    ((unsigned short*)Cv)[rb + col] = f2bf(v > 0.f ? v : 0.f);
                }
            }
        }
    }
}

// ---------------- 256x256 BT GEMM, BK=64, 8 waves ----------------
// One vmcnt(0)+barrier per K-tile (drain covered by previous tile's 64-MFMA
// compute, 2 waves/SIMD); stage tile t+1 right after the barrier (safe: that
// buffer's reads all completed before this barrier). Two phases per tile
// (k-step 0/1): 12 ds_read -> 32 MFMA, setprio around the MFMA cluster.
// EPI: 2 = bf16 relu(v+bias); 3 = f32 atomicAdd (split-K via blockIdx.z).
template <int EPI>
__global__ __launch_bounds__(512, 2) void k_gemm256(
    const unsigned short* __restrict__ A, const unsigned short* __restrict__ B,
    void* __restrict__ Cv, const float* __restrict__ bias,
    int N, int K, int ldA, int ldB)
{
    // [dbuf][half][128 rows][64 cols] bf16, linear; source swizzled so that
    // slot s of row r holds global k-block s ^ ((r>>1)&7).
    __shared__ __align__(16) unsigned short As[2][2][128 * 64];
    __shared__ __align__(16) unsigned short Bs[2][2][128 * 64];
    const int tid = threadIdx.x;
    const int wv = tid >> 6, l = tid & 63;
    const int m0 = blockIdx.y * 256, n0 = blockIdx.x * 256;
    const long koff = (long)blockIdx.z * K;

    const int lr = l & 15, lg = l >> 4;

    // ---- staging constants (lane-linear dest: base + l*16B) ----
    // For (half h, issue L): dest u16 idx = wv*1024 + L*512 + l*8
    //   -> row r = wv*16 + L*8 + (l>>3), slot = l&7
    //   -> must fetch global k-block g = (l&7) ^ (L*4 + (l>>4))
    const int srow = wv * 16 + (l >> 3);         // + L*8
    const int g0 = (l & 7) ^ (l >> 4);           // L=0
    const int g1 = (l & 7) ^ (4 + (l >> 4));     // L=1
    const unsigned short* pA = A + koff + (long)(m0 + srow) * ldA;
    const unsigned short* pB = B + koff + (long)(n0 + srow) * ldB;
    const long l8A = (long)8 * ldA, l128A = (long)128 * ldA;
    const long l8B = (long)8 * ldB, l128B = (long)128 * ldB;
    const int dst0 = wv * 1024;                  // u16; +512 for L=1

    auto stage = [&](int k0, int d) {
        #pragma unroll
        for (int h = 0; h < 2; ++h) {
            gload_lds16(pA + (long)h * l128A + k0 + g0 * 8, &As[d][h][dst0]);
            gload_lds16(pA + (long)h * l128A + l8A + k0 + g1 * 8, &As[d][h][dst0 + 512]);
            gload_lds16(pB + (long)h * l128B + k0 + g0 * 8, &Bs[d][h][dst0]);
            gload_lds16(pB + (long)h * l128B + l8B + k0 + g1 * 8, &Bs[d][h][dst0 + 512]);
        }
    };

    f32x4 acc[8][4] = {};
    const int wh = wv >> 2;              // A half
    const int bh = (wv & 3) >> 1;        // B half
    const int brow0 = (wv & 1) * 64;     // B row offset within half
    const int swz = (lr >> 1) & 7;

    stage(0, 0);

    const int nt = K >> 6;
    int cur = 0;
    for (int t = 0; t < nt; ++t) {
        asm volatile("s_waitcnt vmcnt(0)" ::: "memory");   // tile t landed (issued 1 tile ago)
        __builtin_amdgcn_s_barrier();
        __builtin_amdgcn_sched_barrier(0);
        if (t + 1 < nt) stage((t + 1) << 6, cur ^ 1);      // buf cur^1: reads finished pre-barrier
        const unsigned short* Ah = &As[cur][wh][0];
        const unsigned short* Bh = &Bs[cur][bh][0];
        #pragma unroll
        for (int ks = 0; ks < 2; ++ks) {
            const int kb = ((ks * 4 + lg) ^ swz) * 8;
            bf16x8 af[8], bfr[4];
            #pragma unroll
            for (int fm = 0; fm < 8; ++fm)
                af[fm] = *(const bf16x8*)&Ah[(fm * 16 + lr) * 64 + kb];
            #pragma unroll
            for (int fn = 0; fn < 4; ++fn)
                bfr[fn] = *(const bf16x8*)&Bh[(brow0 + fn * 16 + lr) * 64 + kb];
            asm volatile("s_waitcnt lgkmcnt(0)" ::: "memory");
            __builtin_amdgcn_sched_barrier(0);
            __builtin_amdgcn_s_setprio(1);
            #pragma unroll
            for (int fm = 0; fm < 8; ++fm)
                #pragma unroll
                for (int fn = 0; fn < 4; ++fn)
                    acc[fm][fn] = __builtin_amdgcn_mfma_f32_16x16x32_bf16(af[fm], bfr[fn], acc[fm][fn], 0, 0, 0);
            __builtin_amdgcn_s_setprio(0);
            __builtin_amdgcn_sched_barrier(0);
        }
        cur ^= 1;
    }

    const int wm = (wv >> 2) * 128, wn = (wv & 3) * 64;
    #pragma unroll
    for (int fm = 0; fm < 8; ++fm) {
        #pragma unroll
        for (int r = 0; r < 4; ++r) {
            const int row = m0 + wm + fm * 16 + lg * 4 + r;
            const long rb = (long)row * N;
            #pragma unroll
            for (int fn = 0; fn < 4; ++fn) {
                const int col = n0 + wn + fn * 16 + lr;
                float v = acc[fm][fn][r];
                if (EPI == 2) {
                    v += bias[col];
                    ((unsigned short*)Cv)[rb + col] = f2bf(v > 0.f ? v : 0.f);
                } else {
                    atomicAdd(&((float*)Cv)[rb + col], v);
                }
            }
        }
    }
}

// ---------------- flash attention (causal, q==k tensor) ----------------
#define CEXP 0.18033688f   // 0.125 * log2(e)
#define PSTRIDE 72

__global__ __launch_bounds__(256, 2) void k_attn(
    const unsigned short* __restrict__ qk, const unsigned short* __restrict__ vt,
    unsigned short* __restrict__ ctx)
{
    __shared__ __align__(16) unsigned short Ks[64 * 64];
    __shared__ __align__(16) unsigned short Vs[64 * 64];
    __shared__ __align__(16) unsigned short P[4][16 * PSTRIDE];
    const int tid = threadIdx.x;
    const int wave = tid >> 6, lane = tid & 63;
    const int bh = blockIdx.x >> 3, pairIdx = blockIdx.x & 7;
    const int b = bh >> 4, h = bh & 15;
    const int lr = lane & 15, lg = lane >> 4;

    const int swz = (lr & 7) << 4;
    const int cby0 = (lg * 16) ^ swz;
    const int cby1 = (64 + lg * 16) ^ swz;
    const int srow_l = lane >> 3;
    const int scol = ((lane & 7) * 8) ^ (srow_l << 3);   // u16 units

    unsigned short* Pw = P[wave];
    char* KsB = (char*)Ks;
    char* VsB = (char*)Vs;
    const unsigned short* qbase = qk + ((long)b << 20) + h * 64;
    const unsigned short* vb    = vt + ((long)(b * 16 + h) << 16);

    #pragma unroll 1
    for (int phase = 0; phase < 2; ++phase) {
        const int qb = phase ? (15 - pairIdx) : pairIdx;
        const int q0 = qb << 6;
        const int qw = q0 + wave * 16;

        const unsigned short* qrow = qbase + (long)(qw + lr) * 1024 + lg * 8;
        const bf16x8 aq0 = *(const bf16x8*)qrow;
        const bf16x8 aq1 = *(const bf16x8*)(qrow + 32);

        f32x4 acc[4] = {};
        float mrow[4] = {-1e30f, -1e30f, -1e30f, -1e30f};
        float lrow[4] = {0.f, 0.f, 0.f, 0.f};

        for (int c = 0; c <= qb; ++c) {
            const int k0 = c << 6;
            __syncthreads();
            #pragma unroll
            for (int i = 0; i < 2; ++i) {
                const int row = i * 32 + wave * 8 + srow_l;
                gload_lds16(qbase + (long)(k0 + row) * 1024 + scol,
                            KsB + i * 4096 + wave * 1024);
                gload_lds16(vb + (long)row * 1024 + k0 + scol,
                            VsB + i * 4096 + wave * 1024);
            }
            __syncthreads();

            f32x4 s[4];
            #pragma unroll
            for (int t = 0; t < 4; ++t) {
                const int r = t * 16 + lr;
                bf16x8 bk0 = *(const bf16x8*)(KsB + r * 128 + cby0);
                bf16x8 bk1 = *(const bf16x8*)(KsB + r * 128 + cby1);
                f32x4 z = {};
                z = __builtin_amdgcn_mfma_f32_16x16x32_bf16(aq0, bk0, z, 0, 0, 0);
                s[t] = __builtin_amdgcn_mfma_f32_16x16x32_bf16(aq1, bk1, z, 0, 0, 0);
            }
            if (c == qb) {
                #pragma unroll
                for (int t = 0; t < 4; ++t) {
                    const int col = t * 16 + lr;
                    #pragma unroll
                    for (int r = 0; r < 4; ++r)
                        if (col > wave * 16 + lg * 4 + r) s[t][r] = -1e30f;
                }
            }
            float fac[4];
            #pragma unroll
            for (int r = 0; r < 4; ++r) {
                float v = fmaxf(fmaxf(s[0][r], s[1][r]), fmaxf(s[2][r], s[3][r]));
                v = fmaxf(v, __shfl_xor(v, 1));
                v = fmaxf(v, __shfl_xor(v, 2));
                v = fmaxf(v, __shfl_xor(v, 4));
                v = fmaxf(v, __shfl_xor(v, 8));
                float mn = fmaxf(mrow[r], v);
                fac[r] = exp2f((mrow[r] - mn) * CEXP);
                mrow[r] = mn;
            }
            float psum[4] = {0.f, 0.f, 0.f, 0.f};
            #pragma unroll
            for (int t = 0; t < 4; ++t) {
                #pragma unroll
                for (int r = 0; r < 4; ++r) {
                    float p = exp2f((s[t][r] - mrow[r]) * CEXP);
                    psum[r] += p;
                    Pw[(lg * 4 + r) * PSTRIDE + t * 16 + lr] = f2bf(p);
                }
            }
            #pragma unroll
            for (int r = 0; r < 4; ++r) {
                float v = psum[r];
                v += __shfl_xor(v, 1); v += __shfl_xor(v, 2);
                v += __shfl_xor(v, 4); v += __shfl_xor(v, 8);
                lrow[r] = lrow[r] * fac[r] + v;
            }
            #pragma unroll
            for (int ni = 0; ni < 4; ++ni)
                #pragma unroll
                for (int r = 0; r < 4; ++r)
                    acc[ni][r] *= fac[r];
            const bf16x8 pa0 = *(const bf16x8*)&Pw[lr * PSTRIDE + lg * 8];
            const bf16x8 pa1 = *(const bf16x8*)&Pw[lr * PSTRIDE + 32 + lg * 8];
            #pragma unroll
            for (int ni = 0; ni < 4; ++ni) {
                const int vr = ni * 16 + lr;
                bf16x8 bv0 = *(const bf16x8*)(VsB + vr * 128 + cby0);
                bf16x8 bv1 = *(const bf16x8*)(VsB + vr * 128 + cby1);
                acc[ni] = __builtin_amdgcn_mfma_f32_16x16x32_bf16(pa0, bv0, acc[ni], 0, 0, 0);
                acc[ni] = __builtin_amdgcn_mfma_f32_16x16x32_bf16(pa1, bv1, acc[ni], 0, 0, 0);
            }
        }

        unsigned short* crow = ctx + ((long)(b * 1024 + qw)) * 1024 + h * 64;
        #pragma unroll
        for (int r = 0; r < 4; ++r) {
            const float inv = 1.0f / lrow[r];
            #pragma unroll
            for (int ni = 0; ni < 4; ++ni)
                crow[(long)(lg * 4 + r) * 1024 + ni * 16 + lr] = f2bf(acc[ni][r] * inv);
        }
    }
}

// ---------------- launcher ----------------
extern "C" void kernel_launch(void* const* d_in, const int* in_sizes, int n_in,
                              void* d_out, int out_size, void* d_ws, size_t ws_size,
                              hipStream_t stream)
{
    const float* x   = (const float*)d_in[0];
    const float* Wk  = (const float*)d_in[1];
    const float* Wv  = (const float*)d_in[2];
    const float* Wp  = (const float*)d_in[3];
    const float* bp  = (const float*)d_in[4];
    const float* W1  = (const float*)d_in[5];
    const float* b1  = (const float*)d_in[6];
    const float* W2  = (const float*)d_in[7];
    const float* b2  = (const float*)d_in[8];
    const float* g1  = (const float*)d_in[9];
    const float* be1 = (const float*)d_in[10];
    const float* g2  = (const float*)d_in[11];
    const float* be2 = (const float*)d_in[12];
    float* out = (float*)d_out;

    char* ws = (char*)d_ws;
    const long MB = 1024 * 1024;
    unsigned short* BkT = (unsigned short*)(ws);
    unsigned short* WvT = (unsigned short*)(ws + 2 * MB);
    unsigned short* WpB = (unsigned short*)(ws + 4 * MB);
    unsigned short* W1B = (unsigned short*)(ws + 6 * MB);
    unsigned short* W2B = (unsigned short*)(ws + 14 * MB);
    unsigned short* hB  = (unsigned short*)(ws + 22 * MB);
    unsigned short* qkB = (unsigned short*)(ws + 30 * MB);
    unsigned short* VtB = (unsigned short*)(ws + 38 * MB);
    unsigned short* ctx = (unsigned short*)(ws + 46 * MB);
    unsigned short* ff1 = (unsigned short*)(ws + 30 * MB);  // overlays qk/Vt/ctx
    float* x2   = (float*)(ws + 62 * MB);
    float* psum = (float*)(ws + 78 * MB);
    float* psq  = (float*)(ws + 78 * MB + 128 * 1024);
    float* mean = (float*)(ws + 78 * MB + 256 * 1024);
    float* rstd = (float*)(ws + 78 * MB + 272 * 1024);

    // weight prep
    k_cast_bf16<<<1024, BDIM, 0, stream>>>(Wp, WpB, 262144);
    k_cast_bf16<<<4096, BDIM, 0, stream>>>(W1, W1B, 1048576);
    k_cast_bf16<<<4096, BDIM, 0, stream>>>(W2, W2B, 1048576);
    k_headT<<<dim3(16, 16), BDIM, 0, stream>>>(Wk, BkT);
    k_headT<<<dim3(16, 16), BDIM, 0, stream>>>(Wv, WvT);

    // LN1 (over T axis)
    k_ln_part<<<dim3(4, 8, 4), BDIM, 0, stream>>>(x, psum, psq);
    k_ln_fin<<<16, BDIM, 0, stream>>>(psum, psq, mean, rstd);
    k_ln_apply<<<4096, BDIM, 0, stream>>>(x, mean, rstd, g1, be1, hB);

    // projections
    k_gemm_bt<0><<<dim3(8, 32, 1), BDIM, 0, stream>>>(hB, BkT, qkB, nullptr, nullptr, 1024, 1024, 1024, 1024, 0, 0, 0);
    k_gemm_bt<0><<<dim3(8, 8, 4), BDIM, 0, stream>>>(WvT, hB, VtB, nullptr, nullptr, 1024, 1024, 1024, 1024, 0, MB, MB);

    // flash attention -> ctx bf16 [4096, 1024]
    k_attn<<<512, BDIM, 0, stream>>>(qkB, VtB, ctx);

    // out-proj + bias + residual -> x2 f32
    k_gemm_bt<1><<<dim3(8, 32, 1), BDIM, 0, stream>>>(ctx, WpB, x2, bp, x, 1024, 1024, 1024, 1024, 0, 0, 0);

    // LN2
    k_ln_part<<<dim3(4, 8, 4), BDIM, 0, stream>>>(x2, psum, psq);
    k_ln_fin<<<16, BDIM, 0, stream>>>(psum, psq, mean, rstd);
    k_ln_apply<<<4096, BDIM, 0, stream>>>(x2, mean, rstd, g2, be2, hB);

    // FF1: ff1 = relu(h2 @ W1^T + b1) bf16, 256^2 tiles (grid 16x16)
    k_gemm256<2><<<dim3(16, 16, 1), 512, 0, stream>>>(hB, W1B, ff1, b1, 4096, 1024, 1024, 1024);

    // FF2 split-K=4: out = x2 + b2 (prefill), then out += ff1 @ W2^T (atomic)
    k_addbias<<<4096, BDIM, 0, stream>>>(x2, b2, out);
    k_gemm256<3><<<dim3(4, 16, 4), 512, 0, stream>>>(ff1, W2B, out, nullptr, 1024, 1024, 4096, 4096);
}

// Round 7
// 399.333 us; speedup vs baseline: 1.0525x; 1.0092x over previous
//
#include <hip/hip_runtime.h>
#include <stdint.h>

// Block_32521492365607: pre-LN(T-axis) attention block, MI355X gfx950.
// Round 7 (= round 6 resubmitted; bench infra timed out, no data).
// k_gemm256: 2-tile-deep counted-vmcnt pipeline: vmcnt(8) per K-tile
// (never 0 in steady state), 4 phases of {ds_read, lgkmcnt, setprio,
// 16 MFMA, barrier}, stage(t+2) after last barrier. Fragment reuse:
// 24 ds_read/tile. XCD-bijective block swizzle.
// 128x128 GEMMs + attention unchanged (round-3/5 proven).
//
// WS layout (bytes):
//   0: BkT 2MB | 2MB: WvT 2MB | 4MB: WpB 2MB | 6MB: W1B 8MB | 14MB: W2B 8MB
//   22MB: hB 8MB | 30MB: qk 8MB | 38MB: Vt 8MB | 46MB: ctx 8MB
//   (ff1 bf16 [4096,4096] overlays 30..62MB after qk/Vt/ctx are dead)
//   62MB: x2 f32 16MB | 78MB: ln stats. Total ~78.3MB.

#define BDIM 256

typedef __attribute__((ext_vector_type(8))) __bf16 bf16x8;
typedef __attribute__((ext_vector_type(4))) float f32x4;

__device__ __forceinline__ unsigned short f2bf(float f) {
    unsigned u = __float_as_uint(f);
    u += 0x7fff + ((u >> 16) & 1);   // RNE
    return (unsigned short)(u >> 16);
}

__device__ __forceinline__ void gload_lds16(const void* g, void* l) {
    __builtin_amdgcn_global_load_lds(
        (const __attribute__((address_space(1))) void*)g,
        (__attribute__((address_space(3))) void*)l, 16, 0, 0);
}

// ---------------- weight prep ----------------
__global__ void k_cast_bf16(const float* __restrict__ in, unsigned short* __restrict__ out, int n4) {
    int i = blockIdx.x * BDIM + threadIdx.x;
    if (i >= n4) return;
    float4 v = ((const float4*)in)[i];
    ushort4 o;
    o.x = f2bf(v.x); o.y = f2bf(v.y); o.z = f2bf(v.z); o.w = f2bf(v.w);
    ((ushort4*)out)[i] = o;
}

// W[h][c][d] (16,1024,64) -> out[(h*64+d)*1024 + c] bf16, LDS transpose tile.
__global__ void k_headT(const float* __restrict__ W, unsigned short* __restrict__ out) {
    __shared__ float tile[64][65];
    const int tid = threadIdx.x;
    const int c0 = blockIdx.x * 64, h = blockIdx.y;
    const float* src = W + ((long)h << 16) + (long)c0 * 64;
    #pragma unroll
    for (int j = 0; j < 16; ++j) {
        int idx = j * 256 + tid;
        tile[idx >> 6][idx & 63] = src[idx];
    }
    __syncthreads();
    #pragma unroll
    for (int j = 0; j < 16; ++j) {
        int idx = j * 256 + tid;
        int d = idx >> 6, c = idx & 63;
        out[(long)(h * 64 + d) * 1024 + c0 + c] = f2bf(tile[c][d]);
    }
}

// ---------------- LayerNorm over T axis ----------------
__global__ void k_ln_part(const float* __restrict__ x, float* __restrict__ psum, float* __restrict__ psq) {
    int c = blockIdx.x * BDIM + threadIdx.x;
    int tc = blockIdx.y, b = blockIdx.z;
    const float* p = x + ((long)b << 20) + ((long)tc * 128) * 1024 + c;
    float s = 0.f, ss = 0.f;
    for (int t = 0; t < 128; ++t) {
        float v = p[t * 1024];
        s += v; ss += v * v;
    }
    int o = (b * 8 + tc) * 1024 + c;
    psum[o] = s; psq[o] = ss;
}

__global__ void k_ln_fin(const float* __restrict__ psum, const float* __restrict__ psq,
                         float* __restrict__ mean, float* __restrict__ rstd) {
    int i = blockIdx.x * BDIM + threadIdx.x;  // 4096 = B*C
    int b = i >> 10, c = i & 1023;
    float s = 0.f, ss = 0.f;
    for (int j = 0; j < 8; ++j) {
        s  += psum[(b * 8 + j) * 1024 + c];
        ss += psq[(b * 8 + j) * 1024 + c];
    }
    float m = s * (1.0f / 1024.0f);
    float var = (ss - 1024.0f * m * m) * (1.0f / 1023.0f);   // ddof=1
    mean[i] = m;
    rstd[i] = rsqrtf(var + 1e-5f);
}

__global__ void k_ln_apply(const float* __restrict__ x, const float* __restrict__ mean,
                           const float* __restrict__ rstd, const float* __restrict__ g,
                           const float* __restrict__ beta, unsigned short* __restrict__ out) {
    int i = blockIdx.x * BDIM + threadIdx.x;   // 1M, 4 elems each
    int flat = i << 2;
    int b = flat >> 20, c = flat & 1023;
    float4 xv = ((const float4*)x)[i];
    float4 mv = *(const float4*)&mean[(b << 10) + c];
    float4 rv = *(const float4*)&rstd[(b << 10) + c];
    float4 gv = *(const float4*)&g[c];
    float4 bv = *(const float4*)&beta[c];
    ushort4 o;
    o.x = f2bf(gv.x * (xv.x - mv.x) * rv.x + bv.x);
    o.y = f2bf(gv.y * (xv.y - mv.y) * rv.y + bv.y);
    o.z = f2bf(gv.z * (xv.z - mv.z) * rv.z + bv.z);
    o.w = f2bf(gv.w * (xv.w - mv.w) * rv.w + bv.w);
    ((ushort4*)out)[i] = o;
}

// prefill for split-K FF2: out[i] = res[i] + bias[col]
__global__ void k_addbias(const float* __restrict__ res, const float* __restrict__ bias,
                          float* __restrict__ out) {
    int i = blockIdx.x * BDIM + threadIdx.x;   // 1M float4
    int c = (i << 2) & 1023;
    float4 r = ((const float4*)res)[i];
    float4 bv = *(const float4*)&bias[c];
    r.x += bv.x; r.y += bv.y; r.z += bv.z; r.w += bv.w;
    ((float4*)out)[i] = r;
}

// ---------------- 128x128 BT GEMM (round-3 loop + swizzle) ----------------
// EPI: 0 = bf16 out; 1 = f32 out + bias[col] + res; 2 = bf16 relu(v+bias)
template <int EPI>
__global__ __launch_bounds__(256, 3) void k_gemm_bt(
    const unsigned short* __restrict__ A, const unsigned short* __restrict__ B,
    void* __restrict__ Cv, const float* __restrict__ bias, const float* __restrict__ res,
    int N, int K, int ldA, int ldB, long sA, long sB, long sC)
{
    __shared__ __align__(16) unsigned short As[2][128 * 32];
    __shared__ __align__(16) unsigned short Bs[2][128 * 32];
    const int tid = threadIdx.x;
    const int wave = tid >> 6, lane = tid & 63;
    const long bz = blockIdx.z;
    const int m0 = blockIdx.y * 128, n0 = blockIdx.x * 128;

    const int srow = wave * 16 + (lane >> 2);
    const int kbs = (lane & 3) ^ ((srow >> 1) & 3);
    const unsigned short* gA0 = A + bz * sA + (long)(m0 + srow) * ldA + kbs * 8;
    const unsigned short* gB0 = B + bz * sB + (long)(n0 + srow) * ldB + kbs * 8;
    const long rowoffA = (long)64 * ldA;
    const long rowoffB = (long)64 * ldB;
    const int lofs = wave * 512;

    f32x4 acc[4][4] = {};
    const int wm = (wave >> 1) * 64, wn = (wave & 1) * 64;
    const int lr = lane & 15, lg = lane >> 4;
    const int aoff = (lg ^ ((lr >> 1) & 3)) * 8;

    auto stage = [&](int kt, int buf) {
        gload_lds16(gA0 + kt, &As[buf][lofs]);
        gload_lds16(gA0 + rowoffA + kt, &As[buf][2048 + lofs]);
        gload_lds16(gB0 + kt, &Bs[buf][lofs]);
        gload_lds16(gB0 + rowoffB + kt, &Bs[buf][2048 + lofs]);
    };

    stage(0, 0);
    asm volatile("s_waitcnt vmcnt(0)" ::: "memory");
    __builtin_amdgcn_s_barrier();
    __builtin_amdgcn_sched_barrier(0);

    int cur = 0;
    for (int kt = 0; kt < K; kt += 32) {
        const int nxt = cur ^ 1;
        if (kt + 32 < K) stage(kt + 32, nxt);
        bf16x8 af[4], bfr[4];
        #pragma unroll
        for (int i = 0; i < 4; ++i) {
            af[i]  = *(const bf16x8*)&As[cur][(wm + i * 16 + lr) * 32 + aoff];
            bfr[i] = *(const bf16x8*)&Bs[cur][(wn + i * 16 + lr) * 32 + aoff];
        }
        #pragma unroll
        for (int i = 0; i < 4; ++i)
            #pragma unroll
            for (int j = 0; j < 4; ++j)
                acc[i][j] = __builtin_amdgcn_mfma_f32_16x16x32_bf16(af[i], bfr[j], acc[i][j], 0, 0, 0);
        asm volatile("s_waitcnt vmcnt(0)" ::: "memory");
        __builtin_amdgcn_s_barrier();
        __builtin_amdgcn_sched_barrier(0);
        cur = nxt;
    }

    const int cr0 = lg * 4;
    #pragma unroll
    for (int mi = 0; mi < 4; ++mi) {
        #pragma unroll
        for (int r = 0; r < 4; ++r) {
            const int row = m0 + wm + mi * 16 + cr0 + r;
            const long rb = bz * sC + (long)row * N;
            #pragma unroll
            for (int nj = 0; nj < 4; ++nj) {
                const int col = n0 + wn + nj * 16 + lr;
                float v = acc[mi][nj][r];
                if (EPI == 0) {
                    ((unsigned short*)Cv)[rb + col] = f2bf(v);
                } else if (EPI == 1) {
                    ((float*)Cv)[rb + col] = v + bias[col] + res[rb + col];
                } else {
                    v += bias[col];
                    ((unsigned short*)Cv)[rb + col] = f2bf(v > 0.f ? v : 0.f);
                }
            }
        }
    }
}

// ---------------- 256x256 BT GEMM, BK=64, 8 waves, 2-deep pipeline --------
// Iteration t: vmcnt(8) [tile t retired, t+1 in flight] -> barrier ->
// 4 phases {ds_read subtile, lgkmcnt(0), setprio, 16 MFMA, barrier} ->
// stage(t+2) into dbuf t&1 (all waves past last read via P3 barrier).
// Fragment reuse: P0 reads A(fm0-3)+B(fn0-1); P1 reads B(fn2-3); P2 reads
// A(fm4-7); P3 no reads. LDS swizzle as round 5 (0 conflicts, verified).
// EPI: 2 = bf16 relu(v+bias); 3 = f32 atomicAdd (split-K via blockIdx.z).
template <int EPI>
__global__ __launch_bounds__(512, 2) void k_gemm256(
    const unsigned short* __restrict__ A, const unsigned short* __restrict__ B,
    void* __restrict__ Cv, const float* __restrict__ bias,
    int N, int K, int ldA, int ldB)
{
    __shared__ __align__(16) unsigned short As[2][2][128 * 64];
    __shared__ __align__(16) unsigned short Bs[2][2][128 * 64];
    const int tid = threadIdx.x;
    const int wv = tid >> 6, l = tid & 63;

    // XCD-bijective swizzle (nwg % 8 == 0 for all our grids)
    const int gx = gridDim.x;
    const int nwg = gx * gridDim.y;
    int lin = blockIdx.y * gx + blockIdx.x;
    lin = (lin & 7) * (nwg >> 3) + (lin >> 3);
    const int m0 = (lin / gx) * 256, n0 = (lin % gx) * 256;
    const long koff = (long)blockIdx.z * K;

    const int lr = l & 15, lg = l >> 4;

    // staging (lane-linear dest; source k-block pre-swizzled, round-5 proven)
    const int srow = wv * 16 + (l >> 3);
    const int g0 = (l & 7) ^ (l >> 4);
    const int g1 = (l & 7) ^ (4 + (l >> 4));
    const unsigned short* pA = A + koff + (long)(m0 + srow) * ldA;
    const unsigned short* pB = B + koff + (long)(n0 + srow) * ldB;
    const long l8A = (long)8 * ldA, l128A = (long)128 * ldA;
    const long l8B = (long)8 * ldB, l128B = (long)128 * ldB;
    const int dst0 = wv * 1024;

    auto stage = [&](int k0, int d) {
        #pragma unroll
        for (int h = 0; h < 2; ++h) {
            gload_lds16(pA + (long)h * l128A + k0 + g0 * 8, &As[d][h][dst0]);
            gload_lds16(pA + (long)h * l128A + l8A + k0 + g1 * 8, &As[d][h][dst0 + 512]);
            gload_lds16(pB + (long)h * l128B + k0 + g0 * 8, &Bs[d][h][dst0]);
            gload_lds16(pB + (long)h * l128B + l8B + k0 + g1 * 8, &Bs[d][h][dst0 + 512]);
        }
    };

    f32x4 acc[8][4] = {};
    const int wh = wv >> 2;              // A half
    const int bhf = (wv & 3) >> 1;       // B half
    const int brow0 = (wv & 1) * 64;     // B row offset within half
    const int swz = (lr >> 1) & 7;

    const int nt = K >> 6;               // >= 2 for all our calls
    stage(0, 0);
    stage(64, 1);

    for (int t = 0; t < nt; ++t) {
        const int d = t & 1;
        if (t + 1 < nt) { asm volatile("s_waitcnt vmcnt(8)" ::: "memory"); }
        else            { asm volatile("s_waitcnt vmcnt(0)" ::: "memory"); }
        __builtin_amdgcn_s_barrier();
        __builtin_amdgcn_sched_barrier(0);
        const unsigned short* Ah = &As[d][wh][0];
        const unsigned short* Bh = &Bs[d][bhf][0];

        bf16x8 aLo[4][2], aHi[4][2], b01[2][2], b23[2][2];
        // ---- P0: read A fm0-3 (8) + B fn0-1 (4); MFMA fm0-3 x fn0-1 ----
        #pragma unroll
        for (int fm = 0; fm < 4; ++fm)
            #pragma unroll
            for (int ks = 0; ks < 2; ++ks)
                aLo[fm][ks] = *(const bf16x8*)&Ah[(fm * 16 + lr) * 64 + (((ks * 4 + lg) ^ swz) * 8)];
        #pragma unroll
        for (int fn = 0; fn < 2; ++fn)
            #pragma unroll
            for (int ks = 0; ks < 2; ++ks)
                b01[fn][ks] = *(const bf16x8*)&Bh[(brow0 + fn * 16 + lr) * 64 + (((ks * 4 + lg) ^ swz) * 8)];
        asm volatile("s_waitcnt lgkmcnt(0)" ::: "memory");
        __builtin_amdgcn_sched_barrier(0);
        __builtin_amdgcn_s_setprio(1);
        #pragma unroll
        for (int fm = 0; fm < 4; ++fm)
            #pragma unroll
            for (int fn = 0; fn < 2; ++fn)
                #pragma unroll
                for (int ks = 0; ks < 2; ++ks)
                    acc[fm][fn] = __builtin_amdgcn_mfma_f32_16x16x32_bf16(aLo[fm][ks], b01[fn][ks], acc[fm][fn], 0, 0, 0);
        __builtin_amdgcn_s_setprio(0);
        __builtin_amdgcn_sched_barrier(0);
        __builtin_amdgcn_s_barrier();
        // ---- P1: read B fn2-3 (4); MFMA fm0-3 x fn2-3 ----
        #pragma unroll
        for (int fn = 0; fn < 2; ++fn)
            #pragma unroll
            for (int ks = 0; ks < 2; ++ks)
                b23[fn][ks] = *(const bf16x8*)&Bh[(brow0 + (fn + 2) * 16 + lr) * 64 + (((ks * 4 + lg) ^ swz) * 8)];
        asm volatile("s_waitcnt lgkmcnt(0)" ::: "memory");
        __builtin_amdgcn_sched_barrier(0);
        __builtin_amdgcn_s_setprio(1);
        #pragma unroll
        for (int fm = 0; fm < 4; ++fm)
            #pragma unroll
            for (int fn = 0; fn < 2; ++fn)
                #pragma unroll
                for (int ks = 0; ks < 2; ++ks)
                    acc[fm][fn + 2] = __builtin_amdgcn_mfma_f32_16x16x32_bf16(aLo[fm][ks], b23[fn][ks], acc[fm][fn + 2], 0, 0, 0);
        __builtin_amdgcn_s_setprio(0);
        __builtin_amdgcn_sched_barrier(0);
        __builtin_amdgcn_s_barrier();
        // ---- P2: read A fm4-7 (8); MFMA fm4-7 x fn2-3 ----
        #pragma unroll
        for (int fm = 0; fm < 4; ++fm)
            #pragma unroll
            for (int ks = 0; ks < 2; ++ks)
                aHi[fm][ks] = *(const bf16x8*)&Ah[((fm + 4) * 16 + lr) * 64 + (((ks * 4 + lg) ^ swz) * 8)];
        asm volatile("s_waitcnt lgkmcnt(0)" ::: "memory");
        __builtin_amdgcn_sched_barrier(0);
        __builtin_amdgcn_s_setprio(1);
        #pragma unroll
        for (int fm = 0; fm < 4; ++fm)
            #pragma unroll
            for (int fn = 0; fn < 2; ++fn)
                #pragma unroll
                for (int ks = 0; ks < 2; ++ks)
                    acc[fm + 4][fn + 2] = __builtin_amdgcn_mfma_f32_16x16x32_bf16(aHi[fm][ks], b23[fn][ks], acc[fm + 4][fn + 2], 0, 0, 0);
        __builtin_amdgcn_s_setprio(0);
        __builtin_amdgcn_sched_barrier(0);
        __builtin_amdgcn_s_barrier();
        // ---- P3: no reads; MFMA fm4-7 x fn0-1 ----
        __builtin_amdgcn_s_setprio(1);
        #pragma unroll
        for (int fm = 0; fm < 4; ++fm)
            #pragma unroll
            for (int fn = 0; fn < 2; ++fn)
                #pragma unroll
                for (int ks = 0; ks < 2; ++ks)
                    acc[fm + 4][fn] = __builtin_amdgcn_mfma_f32_16x16x32_bf16(aHi[fm][ks], b01[fn][ks], acc[fm + 4][fn], 0, 0, 0);
        __builtin_amdgcn_s_setprio(0);
        __builtin_amdgcn_sched_barrier(0);
        __builtin_amdgcn_s_barrier();
        // all waves done reading dbuf d -> safe to overwrite
        if (t + 2 < nt) stage((t + 2) << 6, d);
    }

    const int wm = (wv >> 2) * 128, wn = (wv & 3) * 64;
    #pragma unroll
    for (int fm = 0; fm < 8; ++fm) {
        #pragma unroll
        for (int r = 0; r < 4; ++r) {
            const int row = m0 + wm + fm * 16 + lg * 4 + r;
            const long rb = (long)row * N;
            #pragma unroll
            for (int fn = 0; fn < 4; ++fn) {
                const int col = n0 + wn + fn * 16 + lr;
                float v = acc[fm][fn][r];
                if (EPI == 2) {
                    v += bias[col];
                    ((unsigned short*)Cv)[rb + col] = f2bf(v > 0.f ? v : 0.f);
                } else {
                    atomicAdd(&((float*)Cv)[rb + col], v);
                }
            }
        }
    }
}

// ---------------- flash attention (causal, q==k tensor) ----------------
#define CEXP 0.18033688f   // 0.125 * log2(e)
#define PSTRIDE 72

__global__ __launch_bounds__(256, 2) void k_attn(
    const unsigned short* __restrict__ qk, const unsigned short* __restrict__ vt,
    unsigned short* __restrict__ ctx)
{
    __shared__ __align__(16) unsigned short Ks[64 * 64];
    __shared__ __align__(16) unsigned short Vs[64 * 64];
    __shared__ __align__(16) unsigned short P[4][16 * PSTRIDE];
    const int tid = threadIdx.x;
    const int wave = tid >> 6, lane = tid & 63;
    const int bh = blockIdx.x >> 3, pairIdx = blockIdx.x & 7;
    const int b = bh >> 4, h = bh & 15;
    const int lr = lane & 15, lg = lane >> 4;

    const int swz = (lr & 7) << 4;
    const int cby0 = (lg * 16) ^ swz;
    const int cby1 = (64 + lg * 16) ^ swz;
    const int srow_l = lane >> 3;
    const int scol = ((lane & 7) * 8) ^ (srow_l << 3);   // u16 units

    unsigned short* Pw = P[wave];
    char* KsB = (char*)Ks;
    char* VsB = (char*)Vs;
    const unsigned short* qbase = qk + ((long)b << 20) + h * 64;
    const unsigned short* vb    = vt + ((long)(b * 16 + h) << 16);

    #pragma unroll 1
    for (int phase = 0; phase < 2; ++phase) {
        const int qb = phase ? (15 - pairIdx) : pairIdx;
        const int q0 = qb << 6;
        const int qw = q0 + wave * 16;

        const unsigned short* qrow = qbase + (long)(qw + lr) * 1024 + lg * 8;
        const bf16x8 aq0 = *(const bf16x8*)qrow;
        const bf16x8 aq1 = *(const bf16x8*)(qrow + 32);

        f32x4 acc[4] = {};
        float mrow[4] = {-1e30f, -1e30f, -1e30f, -1e30f};
        float lrow[4] = {0.f, 0.f, 0.f, 0.f};

        for (int c = 0; c <= qb; ++c) {
            const int k0 = c << 6;
            __syncthreads();
            #pragma unroll
            for (int i = 0; i < 2; ++i) {
                const int row = i * 32 + wave * 8 + srow_l;
                gload_lds16(qbase + (long)(k0 + row) * 1024 + scol,
                            KsB + i * 4096 + wave * 1024);
                gload_lds16(vb + (long)row * 1024 + k0 + scol,
                            VsB + i * 4096 + wave * 1024);
            }
            __syncthreads();

            f32x4 s[4];
            #pragma unroll
            for (int t = 0; t < 4; ++t) {
                const int r = t * 16 + lr;
                bf16x8 bk0 = *(const bf16x8*)(KsB + r * 128 + cby0);
                bf16x8 bk1 = *(const bf16x8*)(KsB + r * 128 + cby1);
                f32x4 z = {};
                z = __builtin_amdgcn_mfma_f32_16x16x32_bf16(aq0, bk0, z, 0, 0, 0);
                s[t] = __builtin_amdgcn_mfma_f32_16x16x32_bf16(aq1, bk1, z, 0, 0, 0);
            }
            if (c == qb) {
                #pragma unroll
                for (int t = 0; t < 4; ++t) {
                    const int col = t * 16 + lr;
                    #pragma unroll
                    for (int r = 0; r < 4; ++r)
                        if (col > wave * 16 + lg * 4 + r) s[t][r] = -1e30f;
                }
            }
            float fac[4];
            #pragma unroll
            for (int r = 0; r < 4; ++r) {
                float v = fmaxf(fmaxf(s[0][r], s[1][r]), fmaxf(s[2][r], s[3][r]));
                v = fmaxf(v, __shfl_xor(v, 1));
                v = fmaxf(v, __shfl_xor(v, 2));
                v = fmaxf(v, __shfl_xor(v, 4));
                v = fmaxf(v, __shfl_xor(v, 8));
                float mn = fmaxf(mrow[r], v);
                fac[r] = exp2f((mrow[r] - mn) * CEXP);
                mrow[r] = mn;
            }
            float psum[4] = {0.f, 0.f, 0.f, 0.f};
            #pragma unroll
            for (int t = 0; t < 4; ++t) {
                #pragma unroll
                for (int r = 0; r < 4; ++r) {
                    float p = exp2f((s[t][r] - mrow[r]) * CEXP);
                    psum[r] += p;
                    Pw[(lg * 4 + r) * PSTRIDE + t * 16 + lr] = f2bf(p);
                }
            }
            #pragma unroll
            for (int r = 0; r < 4; ++r) {
                float v = psum[r];
                v += __shfl_xor(v, 1); v += __shfl_xor(v, 2);
                v += __shfl_xor(v, 4); v += __shfl_xor(v, 8);
                lrow[r] = lrow[r] * fac[r] + v;
            }
            #pragma unroll
            for (int ni = 0; ni < 4; ++ni)
                #pragma unroll
                for (int r = 0; r < 4; ++r)
                    acc[ni][r] *= fac[r];
            const bf16x8 pa0 = *(const bf16x8*)&Pw[lr * PSTRIDE + lg * 8];
            const bf16x8 pa1 = *(const bf16x8*)&Pw[lr * PSTRIDE + 32 + lg * 8];
            #pragma unroll
            for (int ni = 0; ni < 4; ++ni) {
                const int vr = ni * 16 + lr;
                bf16x8 bv0 = *(const bf16x8*)(VsB + vr * 128 + cby0);
                bf16x8 bv1 = *(const bf16x8*)(VsB + vr * 128 + cby1);
                acc[ni] = __builtin_amdgcn_mfma_f32_16x16x32_bf16(pa0, bv0, acc[ni], 0, 0, 0);
                acc[ni] = __builtin_amdgcn_mfma_f32_16x16x32_bf16(pa1, bv1, acc[ni], 0, 0, 0);
            }
        }

        unsigned short* crow = ctx + ((long)(b * 1024 + qw)) * 1024 + h * 64;
        #pragma unroll
        for (int r = 0; r < 4; ++r) {
            const float inv = 1.0f / lrow[r];
            #pragma unroll
            for (int ni = 0; ni < 4; ++ni)
                crow[(long)(lg * 4 + r) * 1024 + ni * 16 + lr] = f2bf(acc[ni][r] * inv);
        }
    }
}

// ---------------- launcher ----------------
extern "C" void kernel_launch(void* const* d_in, const int* in_sizes, int n_in,
                              void* d_out, int out_size, void* d_ws, size_t ws_size,
                              hipStream_t stream)
{
    const float* x   = (const float*)d_in[0];
    const float* Wk  = (const float*)d_in[1];
    const float* Wv  = (const float*)d_in[2];
    const float* Wp  = (const float*)d_in[3];
    const float* bp  = (const float*)d_in[4];
    const float* W1  = (const float*)d_in[5];
    const float* b1  = (const float*)d_in[6];
    const float* W2  = (const float*)d_in[7];
    const float* b2  = (const float*)d_in[8];
    const float* g1  = (const float*)d_in[9];
    const float* be1 = (const float*)d_in[10];
    const float* g2  = (const float*)d_in[11];
    const float* be2 = (const float*)d_in[12];
    float* out = (float*)d_out;

    char* ws = (char*)d_ws;
    const long MB = 1024 * 1024;
    unsigned short* BkT = (unsigned short*)(ws);
    unsigned short* WvT = (unsigned short*)(ws + 2 * MB);
    unsigned short* WpB = (unsigned short*)(ws + 4 * MB);
    unsigned short* W1B = (unsigned short*)(ws + 6 * MB);
    unsigned short* W2B = (unsigned short*)(ws + 14 * MB);
    unsigned short* hB  = (unsigned short*)(ws + 22 * MB);
    unsigned short* qkB = (unsigned short*)(ws + 30 * MB);
    unsigned short* VtB = (unsigned short*)(ws + 38 * MB);
    unsigned short* ctx = (unsigned short*)(ws + 46 * MB);
    unsigned short* ff1 = (unsigned short*)(ws + 30 * MB);  // overlays qk/Vt/ctx
    float* x2   = (float*)(ws + 62 * MB);
    float* psum = (float*)(ws + 78 * MB);
    float* psq  = (float*)(ws + 78 * MB + 128 * 1024);
    float* mean = (float*)(ws + 78 * MB + 256 * 1024);
    float* rstd = (float*)(ws + 78 * MB + 272 * 1024);

    // weight prep
    k_cast_bf16<<<1024, BDIM, 0, stream>>>(Wp, WpB, 262144);
    k_cast_bf16<<<4096, BDIM, 0, stream>>>(W1, W1B, 1048576);
    k_cast_bf16<<<4096, BDIM, 0, stream>>>(W2, W2B, 1048576);
    k_headT<<<dim3(16, 16), BDIM, 0, stream>>>(Wk, BkT);
    k_headT<<<dim3(16, 16), BDIM, 0, stream>>>(Wv, WvT);

    // LN1 (over T axis)
    k_ln_part<<<dim3(4, 8, 4), BDIM, 0, stream>>>(x, psum, psq);
    k_ln_fin<<<16, BDIM, 0, stream>>>(psum, psq, mean, rstd);
    k_ln_apply<<<4096, BDIM, 0, stream>>>(x, mean, rstd, g1, be1, hB);

    // projections
    k_gemm_bt<0><<<dim3(8, 32, 1), BDIM, 0, stream>>>(hB, BkT, qkB, nullptr, nullptr, 1024, 1024, 1024, 1024, 0, 0, 0);
    k_gemm_bt<0><<<dim3(8, 8, 4), BDIM, 0, stream>>>(WvT, hB, VtB, nullptr, nullptr, 1024, 1024, 1024, 1024, 0, MB, MB);

    // flash attention -> ctx bf16 [4096, 1024]
    k_attn<<<512, BDIM, 0, stream>>>(qkB, VtB, ctx);

    // out-proj + bias + residual -> x2 f32
    k_gemm_bt<1><<<dim3(8, 32, 1), BDIM, 0, stream>>>(ctx, WpB, x2, bp, x, 1024, 1024, 1024, 1024, 0, 0, 0);

    // LN2
    k_ln_part<<<dim3(4, 8, 4), BDIM, 0, stream>>>(x2, psum, psq);
    k_ln_fin<<<16, BDIM, 0, stream>>>(psum, psq, mean, rstd);
    k_ln_apply<<<4096, BDIM, 0, stream>>>(x2, mean, rstd, g2, be2, hB);

    // FF1: ff1 = relu(h2 @ W1^T + b1) bf16, 256^2 tiles (grid 16x16)
    k_gemm256<2><<<dim3(16, 16, 1), 512, 0, stream>>>(hB, W1B, ff1, b1, 4096, 1024, 1024, 1024);

    // FF2 split-K=4: out = x2 + b2 (prefill), then out += ff1 @ W2^T (atomic)
    k_addbias<<<4096, BDIM, 0, stream>>>(x2, b2, out);
    k_gemm256<3><<<dim3(4, 16, 4), 512, 0, stream>>>(ff1, W2B, out, nullptr, 1024, 1024, 4096, 4096);
}

// Round 8
// 393.580 us; speedup vs baseline: 1.0679x; 1.0146x over previous
//
#include <hip/hip_runtime.h>
#include <stdint.h>

// Block_32521492365607: pre-LN(T-axis) attention block, MI355X gfx950.
// Round 8: k_gemm256 simplified to the T3-minimum 2-phase loop (m248v2:
// 655 TF @256^2 K=1024): ONE barrier + ONE vmcnt(0) per K-tile, two
// ks-chunks gated only by per-wave lgkmcnt (waves drift; MFMA overlaps
// other wave's reads). Removed per-phase barriers (r7's 15%-util bug).
// 128x128 GEMMs + attention unchanged (round-3/5 proven).
//
// WS layout (bytes):
//   0: BkT 2MB | 2MB: WvT 2MB | 4MB: WpB 2MB | 6MB: W1B 8MB | 14MB: W2B 8MB
//   22MB: hB 8MB | 30MB: qk 8MB | 38MB: Vt 8MB | 46MB: ctx 8MB
//   (ff1 bf16 [4096,4096] overlays 30..62MB after qk/Vt/ctx are dead)
//   62MB: x2 f32 16MB | 78MB: ln stats. Total ~78.3MB.

#define BDIM 256

typedef __attribute__((ext_vector_type(8))) __bf16 bf16x8;
typedef __attribute__((ext_vector_type(4))) float f32x4;

__device__ __forceinline__ unsigned short f2bf(float f) {
    unsigned u = __float_as_uint(f);
    u += 0x7fff + ((u >> 16) & 1);   // RNE
    return (unsigned short)(u >> 16);
}

__device__ __forceinline__ void gload_lds16(const void* g, void* l) {
    __builtin_amdgcn_global_load_lds(
        (const __attribute__((address_space(1))) void*)g,
        (__attribute__((address_space(3))) void*)l, 16, 0, 0);
}

// ---------------- weight prep ----------------
__global__ void k_cast_bf16(const float* __restrict__ in, unsigned short* __restrict__ out, int n4) {
    int i = blockIdx.x * BDIM + threadIdx.x;
    if (i >= n4) return;
    float4 v = ((const float4*)in)[i];
    ushort4 o;
    o.x = f2bf(v.x); o.y = f2bf(v.y); o.z = f2bf(v.z); o.w = f2bf(v.w);
    ((ushort4*)out)[i] = o;
}

// W[h][c][d] (16,1024,64) -> out[(h*64+d)*1024 + c] bf16, LDS transpose tile.
__global__ void k_headT(const float* __restrict__ W, unsigned short* __restrict__ out) {
    __shared__ float tile[64][65];
    const int tid = threadIdx.x;
    const int c0 = blockIdx.x * 64, h = blockIdx.y;
    const float* src = W + ((long)h << 16) + (long)c0 * 64;
    #pragma unroll
    for (int j = 0; j < 16; ++j) {
        int idx = j * 256 + tid;
        tile[idx >> 6][idx & 63] = src[idx];
    }
    __syncthreads();
    #pragma unroll
    for (int j = 0; j < 16; ++j) {
        int idx = j * 256 + tid;
        int d = idx >> 6, c = idx & 63;
        out[(long)(h * 64 + d) * 1024 + c0 + c] = f2bf(tile[c][d]);
    }
}

// ---------------- LayerNorm over T axis ----------------
__global__ void k_ln_part(const float* __restrict__ x, float* __restrict__ psum, float* __restrict__ psq) {
    int c = blockIdx.x * BDIM + threadIdx.x;
    int tc = blockIdx.y, b = blockIdx.z;
    const float* p = x + ((long)b << 20) + ((long)tc * 128) * 1024 + c;
    float s = 0.f, ss = 0.f;
    for (int t = 0; t < 128; ++t) {
        float v = p[t * 1024];
        s += v; ss += v * v;
    }
    int o = (b * 8 + tc) * 1024 + c;
    psum[o] = s; psq[o] = ss;
}

__global__ void k_ln_fin(const float* __restrict__ psum, const float* __restrict__ psq,
                         float* __restrict__ mean, float* __restrict__ rstd) {
    int i = blockIdx.x * BDIM + threadIdx.x;  // 4096 = B*C
    int b = i >> 10, c = i & 1023;
    float s = 0.f, ss = 0.f;
    for (int j = 0; j < 8; ++j) {
        s  += psum[(b * 8 + j) * 1024 + c];
        ss += psq[(b * 8 + j) * 1024 + c];
    }
    float m = s * (1.0f / 1024.0f);
    float var = (ss - 1024.0f * m * m) * (1.0f / 1023.0f);   // ddof=1
    mean[i] = m;
    rstd[i] = rsqrtf(var + 1e-5f);
}

__global__ void k_ln_apply(const float* __restrict__ x, const float* __restrict__ mean,
                           const float* __restrict__ rstd, const float* __restrict__ g,
                           const float* __restrict__ beta, unsigned short* __restrict__ out) {
    int i = blockIdx.x * BDIM + threadIdx.x;   // 1M, 4 elems each
    int flat = i << 2;
    int b = flat >> 20, c = flat & 1023;
    float4 xv = ((const float4*)x)[i];
    float4 mv = *(const float4*)&mean[(b << 10) + c];
    float4 rv = *(const float4*)&rstd[(b << 10) + c];
    float4 gv = *(const float4*)&g[c];
    float4 bv = *(const float4*)&beta[c];
    ushort4 o;
    o.x = f2bf(gv.x * (xv.x - mv.x) * rv.x + bv.x);
    o.y = f2bf(gv.y * (xv.y - mv.y) * rv.y + bv.y);
    o.z = f2bf(gv.z * (xv.z - mv.z) * rv.z + bv.z);
    o.w = f2bf(gv.w * (xv.w - mv.w) * rv.w + bv.w);
    ((ushort4*)out)[i] = o;
}

// prefill for split-K FF2: out[i] = res[i] + bias[col]
__global__ void k_addbias(const float* __restrict__ res, const float* __restrict__ bias,
                          float* __restrict__ out) {
    int i = blockIdx.x * BDIM + threadIdx.x;   // 1M float4
    int c = (i << 2) & 1023;
    float4 r = ((const float4*)res)[i];
    float4 bv = *(const float4*)&bias[c];
    r.x += bv.x; r.y += bv.y; r.z += bv.z; r.w += bv.w;
    ((float4*)out)[i] = r;
}

// ---------------- 128x128 BT GEMM (round-3 loop + swizzle) ----------------
// EPI: 0 = bf16 out; 1 = f32 out + bias[col] + res; 2 = bf16 relu(v+bias)
template <int EPI>
__global__ __launch_bounds__(256, 3) void k_gemm_bt(
    const unsigned short* __restrict__ A, const unsigned short* __restrict__ B,
    void* __restrict__ Cv, const float* __restrict__ bias, const float* __restrict__ res,
    int N, int K, int ldA, int ldB, long sA, long sB, long sC)
{
    __shared__ __align__(16) unsigned short As[2][128 * 32];
    __shared__ __align__(16) unsigned short Bs[2][128 * 32];
    const int tid = threadIdx.x;
    const int wave = tid >> 6, lane = tid & 63;
    const long bz = blockIdx.z;
    const int m0 = blockIdx.y * 128, n0 = blockIdx.x * 128;

    const int srow = wave * 16 + (lane >> 2);
    const int kbs = (lane & 3) ^ ((srow >> 1) & 3);
    const unsigned short* gA0 = A + bz * sA + (long)(m0 + srow) * ldA + kbs * 8;
    const unsigned short* gB0 = B + bz * sB + (long)(n0 + srow) * ldB + kbs * 8;
    const long rowoffA = (long)64 * ldA;
    const long rowoffB = (long)64 * ldB;
    const int lofs = wave * 512;

    f32x4 acc[4][4] = {};
    const int wm = (wave >> 1) * 64, wn = (wave & 1) * 64;
    const int lr = lane & 15, lg = lane >> 4;
    const int aoff = (lg ^ ((lr >> 1) & 3)) * 8;

    auto stage = [&](int kt, int buf) {
        gload_lds16(gA0 + kt, &As[buf][lofs]);
        gload_lds16(gA0 + rowoffA + kt, &As[buf][2048 + lofs]);
        gload_lds16(gB0 + kt, &Bs[buf][lofs]);
        gload_lds16(gB0 + rowoffB + kt, &Bs[buf][2048 + lofs]);
    };

    stage(0, 0);
    asm volatile("s_waitcnt vmcnt(0)" ::: "memory");
    __builtin_amdgcn_s_barrier();
    __builtin_amdgcn_sched_barrier(0);

    int cur = 0;
    for (int kt = 0; kt < K; kt += 32) {
        const int nxt = cur ^ 1;
        if (kt + 32 < K) stage(kt + 32, nxt);
        bf16x8 af[4], bfr[4];
        #pragma unroll
        for (int i = 0; i < 4; ++i) {
            af[i]  = *(const bf16x8*)&As[cur][(wm + i * 16 + lr) * 32 + aoff];
            bfr[i] = *(const bf16x8*)&Bs[cur][(wn + i * 16 + lr) * 32 + aoff];
        }
        #pragma unroll
        for (int i = 0; i < 4; ++i)
            #pragma unroll
            for (int j = 0; j < 4; ++j)
                acc[i][j] = __builtin_amdgcn_mfma_f32_16x16x32_bf16(af[i], bfr[j], acc[i][j], 0, 0, 0);
        asm volatile("s_waitcnt vmcnt(0)" ::: "memory");
        __builtin_amdgcn_s_barrier();
        __builtin_amdgcn_sched_barrier(0);
        cur = nxt;
    }

    const int cr0 = lg * 4;
    #pragma unroll
    for (int mi = 0; mi < 4; ++mi) {
        #pragma unroll
        for (int r = 0; r < 4; ++r) {
            const int row = m0 + wm + mi * 16 + cr0 + r;
            const long rb = bz * sC + (long)row * N;
            #pragma unroll
            for (int nj = 0; nj < 4; ++nj) {
                const int col = n0 + wn + nj * 16 + lr;
                float v = acc[mi][nj][r];
                if (EPI == 0) {
                    ((unsigned short*)Cv)[rb + col] = f2bf(v);
                } else if (EPI == 1) {
                    ((float*)Cv)[rb + col] = v + bias[col] + res[rb + col];
                } else {
                    v += bias[col];
                    ((unsigned short*)Cv)[rb + col] = f2bf(v > 0.f ? v : 0.f);
                }
            }
        }
    }
}

// ---------------- 256x256 BT GEMM, BK=64, 8 waves, T3-minimum loop --------
// Per K-tile: STAGE(t+1, buf^1) first; two ks-chunks {12 ds_read_b128,
// lgkmcnt(0)+sched_barrier, setprio, 32 MFMA} gated per-wave only (no
// barrier between -> waves drift, MFMA hides other wave's reads/stage);
// ONE vmcnt(0) + ONE s_barrier at tile end. (m248v2: 655 TF at this shape.)
// Race-free: tile-end barrier orders all reads of buf before next STAGE
// overwrites it; vmcnt(0) before barrier orders STAGE(buf^1) writes before
// next tile reads. LDS swizzle as round 5/7 (0 conflicts, verified).
// EPI: 2 = bf16 relu(v+bias); 3 = f32 atomicAdd (split-K via blockIdx.z).
template <int EPI>
__global__ __launch_bounds__(512, 2) void k_gemm256(
    const unsigned short* __restrict__ A, const unsigned short* __restrict__ B,
    void* __restrict__ Cv, const float* __restrict__ bias,
    int N, int K, int ldA, int ldB)
{
    __shared__ __align__(16) unsigned short As[2][2][128 * 64];
    __shared__ __align__(16) unsigned short Bs[2][2][128 * 64];
    const int tid = threadIdx.x;
    const int wv = tid >> 6, l = tid & 63;

    // XCD-bijective swizzle (nwg % 8 == 0 for all our grids)
    const int gx = gridDim.x;
    const int nwg = gx * gridDim.y;
    int lin = blockIdx.y * gx + blockIdx.x;
    lin = (lin & 7) * (nwg >> 3) + (lin >> 3);
    const int m0 = (lin / gx) * 256, n0 = (lin % gx) * 256;
    const long koff = (long)blockIdx.z * K;

    const int lr = l & 15, lg = l >> 4;

    // staging (lane-linear dest; source k-block pre-swizzled, round-5 proven)
    const int srow = wv * 16 + (l >> 3);
    const int g0 = (l & 7) ^ (l >> 4);
    const int g1 = (l & 7) ^ (4 + (l >> 4));
    const unsigned short* pA = A + koff + (long)(m0 + srow) * ldA;
    const unsigned short* pB = B + koff + (long)(n0 + srow) * ldB;
    const long l8A = (long)8 * ldA, l128A = (long)128 * ldA;
    const long l8B = (long)8 * ldB, l128B = (long)128 * ldB;
    const int dst0 = wv * 1024;

    auto stage = [&](int k0, int d) {
        #pragma unroll
        for (int h = 0; h < 2; ++h) {
            gload_lds16(pA + (long)h * l128A + k0 + g0 * 8, &As[d][h][dst0]);
            gload_lds16(pA + (long)h * l128A + l8A + k0 + g1 * 8, &As[d][h][dst0 + 512]);
            gload_lds16(pB + (long)h * l128B + k0 + g0 * 8, &Bs[d][h][dst0]);
            gload_lds16(pB + (long)h * l128B + l8B + k0 + g1 * 8, &Bs[d][h][dst0 + 512]);
        }
    };

    f32x4 acc[8][4] = {};
    const int wh = wv >> 2;              // A half
    const int bhf = (wv & 3) >> 1;       // B half
    const int brow0 = (wv & 1) * 64;     // B row offset within half
    const int swz = (lr >> 1) & 7;

    const int nt = K >> 6;               // >= 2 for all our calls
    stage(0, 0);
    asm volatile("s_waitcnt vmcnt(0)" ::: "memory");
    __builtin_amdgcn_s_barrier();
    __builtin_amdgcn_sched_barrier(0);

    for (int t = 0; t < nt; ++t) {
        const int d = t & 1;
        if (t + 1 < nt) stage((t + 1) << 6, d ^ 1);   // issue before compute
        const unsigned short* Ah = &As[d][wh][0];
        const unsigned short* Bh = &Bs[d][bhf][0];
        #pragma unroll
        for (int ks = 0; ks < 2; ++ks) {
            const int kb = ((ks * 4 + lg) ^ swz) * 8;
            bf16x8 af[8], bfr[4];
            #pragma unroll
            for (int fm = 0; fm < 8; ++fm)
                af[fm] = *(const bf16x8*)&Ah[(fm * 16 + lr) * 64 + kb];
            #pragma unroll
            for (int fn = 0; fn < 4; ++fn)
                bfr[fn] = *(const bf16x8*)&Bh[(brow0 + fn * 16 + lr) * 64 + kb];
            asm volatile("s_waitcnt lgkmcnt(0)" ::: "memory");
            __builtin_amdgcn_sched_barrier(0);        // rule #18: pin MFMA after wait
            __builtin_amdgcn_s_setprio(1);
            #pragma unroll
            for (int fm = 0; fm < 8; ++fm)
                #pragma unroll
                for (int fn = 0; fn < 4; ++fn)
                    acc[fm][fn] = __builtin_amdgcn_mfma_f32_16x16x32_bf16(af[fm], bfr[fn], acc[fm][fn], 0, 0, 0);
            __builtin_amdgcn_s_setprio(0);
            __builtin_amdgcn_sched_barrier(0);
        }
        asm volatile("s_waitcnt vmcnt(0)" ::: "memory");   // stage(t+1) landed
        __builtin_amdgcn_s_barrier();                      // all reads of buf d done
        __builtin_amdgcn_sched_barrier(0);
    }

    const int wm = (wv >> 2) * 128, wn = (wv & 3) * 64;
    #pragma unroll
    for (int fm = 0; fm < 8; ++fm) {
        #pragma unroll
        for (int r = 0; r < 4; ++r) {
            const int row = m0 + wm + fm * 16 + lg * 4 + r;
            const long rb = (long)row * N;
            #pragma unroll
            for (int fn = 0; fn < 4; ++fn) {
                const int col = n0 + wn + fn * 16 + lr;
                float v = acc[fm][fn][r];
                if (EPI == 2) {
                    v += bias[col];
                    ((unsigned short*)Cv)[rb + col] = f2bf(v > 0.f ? v : 0.f);
                } else {
                    atomicAdd(&((float*)Cv)[rb + col], v);
                }
            }
        }
    }
}

// ---------------- flash attention (causal, q==k tensor) ----------------
#define CEXP 0.18033688f   // 0.125 * log2(e)
#define PSTRIDE 72

__global__ __launch_bounds__(256, 2) void k_attn(
    const unsigned short* __restrict__ qk, const unsigned short* __restrict__ vt,
    unsigned short* __restrict__ ctx)
{
    __shared__ __align__(16) unsigned short Ks[64 * 64];
    __shared__ __align__(16) unsigned short Vs[64 * 64];
    __shared__ __align__(16) unsigned short P[4][16 * PSTRIDE];
    const int tid = threadIdx.x;
    const int wave = tid >> 6, lane = tid & 63;
    const int bh = blockIdx.x >> 3, pairIdx = blockIdx.x & 7;
    const int b = bh >> 4, h = bh & 15;
    const int lr = lane & 15, lg = lane >> 4;

    const int swz = (lr & 7) << 4;
    const int cby0 = (lg * 16) ^ swz;
    const int cby1 = (64 + lg * 16) ^ swz;
    const int srow_l = lane >> 3;
    const int scol = ((lane & 7) * 8) ^ (srow_l << 3);   // u16 units

    unsigned short* Pw = P[wave];
    char* KsB = (char*)Ks;
    char* VsB = (char*)Vs;
    const unsigned short* qbase = qk + ((long)b << 20) + h * 64;
    const unsigned short* vb    = vt + ((long)(b * 16 + h) << 16);

    #pragma unroll 1
    for (int phase = 0; phase < 2; ++phase) {
        const int qb = phase ? (15 - pairIdx) : pairIdx;
        const int q0 = qb << 6;
        const int qw = q0 + wave * 16;

        const unsigned short* qrow = qbase + (long)(qw + lr) * 1024 + lg * 8;
        const bf16x8 aq0 = *(const bf16x8*)qrow;
        const bf16x8 aq1 = *(const bf16x8*)(qrow + 32);

        f32x4 acc[4] = {};
        float mrow[4] = {-1e30f, -1e30f, -1e30f, -1e30f};
        float lrow[4] = {0.f, 0.f, 0.f, 0.f};

        for (int c = 0; c <= qb; ++c) {
            const int k0 = c << 6;
            __syncthreads();
            #pragma unroll
            for (int i = 0; i < 2; ++i) {
                const int row = i * 32 + wave * 8 + srow_l;
                gload_lds16(qbase + (long)(k0 + row) * 1024 + scol,
                            KsB + i * 4096 + wave * 1024);
                gload_lds16(vb + (long)row * 1024 + k0 + scol,
                            VsB + i * 4096 + wave * 1024);
            }
            __syncthreads();

            f32x4 s[4];
            #pragma unroll
            for (int t = 0; t < 4; ++t) {
                const int r = t * 16 + lr;
                bf16x8 bk0 = *(const bf16x8*)(KsB + r * 128 + cby0);
                bf16x8 bk1 = *(const bf16x8*)(KsB + r * 128 + cby1);
                f32x4 z = {};
                z = __builtin_amdgcn_mfma_f32_16x16x32_bf16(aq0, bk0, z, 0, 0, 0);
                s[t] = __builtin_amdgcn_mfma_f32_16x16x32_bf16(aq1, bk1, z, 0, 0, 0);
            }
            if (c == qb) {
                #pragma unroll
                for (int t = 0; t < 4; ++t) {
                    const int col = t * 16 + lr;
                    #pragma unroll
                    for (int r = 0; r < 4; ++r)
                        if (col > wave * 16 + lg * 4 + r) s[t][r] = -1e30f;
                }
            }
            float fac[4];
            #pragma unroll
            for (int r = 0; r < 4; ++r) {
                float v = fmaxf(fmaxf(s[0][r], s[1][r]), fmaxf(s[2][r], s[3][r]));
                v = fmaxf(v, __shfl_xor(v, 1));
                v = fmaxf(v, __shfl_xor(v, 2));
                v = fmaxf(v, __shfl_xor(v, 4));
                v = fmaxf(v, __shfl_xor(v, 8));
                float mn = fmaxf(mrow[r], v);
                fac[r] = exp2f((mrow[r] - mn) * CEXP);
                mrow[r] = mn;
            }
            float psum[4] = {0.f, 0.f, 0.f, 0.f};
            #pragma unroll
            for (int t = 0; t < 4; ++t) {
                #pragma unroll
                for (int r = 0; r < 4; ++r) {
                    float p = exp2f((s[t][r] - mrow[r]) * CEXP);
                    psum[r] += p;
                    Pw[(lg * 4 + r) * PSTRIDE + t * 16 + lr] = f2bf(p);
                }
            }
            #pragma unroll
            for (int r = 0; r < 4; ++r) {
                float v = psum[r];
                v += __shfl_xor(v, 1); v += __shfl_xor(v, 2);
                v += __shfl_xor(v, 4); v += __shfl_xor(v, 8);
                lrow[r] = lrow[r] * fac[r] + v;
            }
            #pragma unroll
            for (int ni = 0; ni < 4; ++ni)
                #pragma unroll
                for (int r = 0; r < 4; ++r)
                    acc[ni][r] *= fac[r];
            const bf16x8 pa0 = *(const bf16x8*)&Pw[lr * PSTRIDE + lg * 8];
            const bf16x8 pa1 = *(const bf16x8*)&Pw[lr * PSTRIDE + 32 + lg * 8];
            #pragma unroll
            for (int ni = 0; ni < 4; ++ni) {
                const int vr = ni * 16 + lr;
                bf16x8 bv0 = *(const bf16x8*)(VsB + vr * 128 + cby0);
                bf16x8 bv1 = *(const bf16x8*)(VsB + vr * 128 + cby1);
                acc[ni] = __builtin_amdgcn_mfma_f32_16x16x32_bf16(pa0, bv0, acc[ni], 0, 0, 0);
                acc[ni] = __builtin_amdgcn_mfma_f32_16x16x32_bf16(pa1, bv1, acc[ni], 0, 0, 0);
            }
        }

        unsigned short* crow = ctx + ((long)(b * 1024 + qw)) * 1024 + h * 64;
        #pragma unroll
        for (int r = 0; r < 4; ++r) {
            const float inv = 1.0f / lrow[r];
            #pragma unroll
            for (int ni = 0; ni < 4; ++ni)
                crow[(long)(lg * 4 + r) * 1024 + ni * 16 + lr] = f2bf(acc[ni][r] * inv);
        }
    }
}

// ---------------- launcher ----------------
extern "C" void kernel_launch(void* const* d_in, const int* in_sizes, int n_in,
                              void* d_out, int out_size, void* d_ws, size_t ws_size,
                              hipStream_t stream)
{
    const float* x   = (const float*)d_in[0];
    const float* Wk  = (const float*)d_in[1];
    const float* Wv  = (const float*)d_in[2];
    const float* Wp  = (const float*)d_in[3];
    const float* bp  = (const float*)d_in[4];
    const float* W1  = (const float*)d_in[5];
    const float* b1  = (const float*)d_in[6];
    const float* W2  = (const float*)d_in[7];
    const float* b2  = (const float*)d_in[8];
    const float* g1  = (const float*)d_in[9];
    const float* be1 = (const float*)d_in[10];
    const float* g2  = (const float*)d_in[11];
    const float* be2 = (const float*)d_in[12];
    float* out = (float*)d_out;

    char* ws = (char*)d_ws;
    const long MB = 1024 * 1024;
    unsigned short* BkT = (unsigned short*)(ws);
    unsigned short* WvT = (unsigned short*)(ws + 2 * MB);
    unsigned short* WpB = (unsigned short*)(ws + 4 * MB);
    unsigned short* W1B = (unsigned short*)(ws + 6 * MB);
    unsigned short* W2B = (unsigned short*)(ws + 14 * MB);
    unsigned short* hB  = (unsigned short*)(ws + 22 * MB);
    unsigned short* qkB = (unsigned short*)(ws + 30 * MB);
    unsigned short* VtB = (unsigned short*)(ws + 38 * MB);
    unsigned short* ctx = (unsigned short*)(ws + 46 * MB);
    unsigned short* ff1 = (unsigned short*)(ws + 30 * MB);  // overlays qk/Vt/ctx
    float* x2   = (float*)(ws + 62 * MB);
    float* psum = (float*)(ws + 78 * MB);
    float* psq  = (float*)(ws + 78 * MB + 128 * 1024);
    float* mean = (float*)(ws + 78 * MB + 256 * 1024);
    float* rstd = (float*)(ws + 78 * MB + 272 * 1024);

    // weight prep
    k_cast_bf16<<<1024, BDIM, 0, stream>>>(Wp, WpB, 262144);
    k_cast_bf16<<<4096, BDIM, 0, stream>>>(W1, W1B, 1048576);
    k_cast_bf16<<<4096, BDIM, 0, stream>>>(W2, W2B, 1048576);
    k_headT<<<dim3(16, 16), BDIM, 0, stream>>>(Wk, BkT);
    k_headT<<<dim3(16, 16), BDIM, 0, stream>>>(Wv, WvT);

    // LN1 (over T axis)
    k_ln_part<<<dim3(4, 8, 4), BDIM, 0, stream>>>(x, psum, psq);
    k_ln_fin<<<16, BDIM, 0, stream>>>(psum, psq, mean, rstd);
    k_ln_apply<<<4096, BDIM, 0, stream>>>(x, mean, rstd, g1, be1, hB);

    // projections
    k_gemm_bt<0><<<dim3(8, 32, 1), BDIM, 0, stream>>>(hB, BkT, qkB, nullptr, nullptr, 1024, 1024, 1024, 1024, 0, 0, 0);
    k_gemm_bt<0><<<dim3(8, 8, 4), BDIM, 0, stream>>>(WvT, hB, VtB, nullptr, nullptr, 1024, 1024, 1024, 1024, 0, MB, MB);

    // flash attention -> ctx bf16 [4096, 1024]
    k_attn<<<512, BDIM, 0, stream>>>(qkB, VtB, ctx);

    // out-proj + bias + residual -> x2 f32
    k_gemm_bt<1><<<dim3(8, 32, 1), BDIM, 0, stream>>>(ctx, WpB, x2, bp, x, 1024, 1024, 1024, 1024, 0, 0, 0);

    // LN2
    k_ln_part<<<dim3(4, 8, 4), BDIM, 0, stream>>>(x2, psum, psq);
    k_ln_fin<<<16, BDIM, 0, stream>>>(psum, psq, mean, rstd);
    k_ln_apply<<<4096, BDIM, 0, stream>>>(x2, mean, rstd, g2, be2, hB);

    // FF1: ff1 = relu(h2 @ W1^T + b1) bf16, 256^2 tiles (grid 16x16)
    k_gemm256<2><<<dim3(16, 16, 1), 512, 0, stream>>>(hB, W1B, ff1, b1, 4096, 1024, 1024, 1024);

    // FF2 split-K=4: out = x2 + b2 (prefill), then out += ff1 @ W2^T (atomic)
    k_addbias<<<4096, BDIM, 0, stream>>>(x2, b2, out);
    k_gemm256<3><<<dim3(4, 16, 4), 512, 0, stream>>>(ff1, W2B, out, nullptr, 1024, 1024, 4096, 4096);
}

// Round 9
// 366.129 us; speedup vs baseline: 1.1480x; 1.0750x over previous
//
#include <hip/hip_runtime.h>
#include <stdint.h>

// Block_32521492365607: pre-LN(T-axis) attention block, MI355X gfx950.
// Round 9: single GEMM workhorse = 128x128 tile, BK=64, 64KB LDS,
// launch_bounds(256,2) -> 2 blocks/CU (the m97/m114 cross-block overlap
// regime r5-r8's 128KB 256^2 kernel could never reach). T3-minimum loop.
// FF1 grid 1024 (2 resident + 2 queued/CU); FF2 split-K=2 (512 blocks,
// atomic WRITE 32MB). k_gemm256 removed. Attention/LN/prep unchanged.
//
// WS layout (bytes):
//   0: BkT 2MB | 2MB: WvT 2MB | 4MB: WpB 2MB | 6MB: W1B 8MB | 14MB: W2B 8MB
//   22MB: hB 8MB | 30MB: qk 8MB | 38MB: Vt 8MB | 46MB: ctx 8MB
//   (ff1 bf16 [4096,4096] overlays 30..62MB after qk/Vt/ctx are dead)
//   62MB: x2 f32 16MB | 78MB: ln stats. Total ~78.3MB.

#define BDIM 256

typedef __attribute__((ext_vector_type(8))) __bf16 bf16x8;
typedef __attribute__((ext_vector_type(4))) float f32x4;

__device__ __forceinline__ unsigned short f2bf(float f) {
    unsigned u = __float_as_uint(f);
    u += 0x7fff + ((u >> 16) & 1);   // RNE
    return (unsigned short)(u >> 16);
}

__device__ __forceinline__ void gload_lds16(const void* g, void* l) {
    __builtin_amdgcn_global_load_lds(
        (const __attribute__((address_space(1))) void*)g,
        (__attribute__((address_space(3))) void*)l, 16, 0, 0);
}

// ---------------- weight prep ----------------
__global__ void k_cast_bf16(const float* __restrict__ in, unsigned short* __restrict__ out, int n4) {
    int i = blockIdx.x * BDIM + threadIdx.x;
    if (i >= n4) return;
    float4 v = ((const float4*)in)[i];
    ushort4 o;
    o.x = f2bf(v.x); o.y = f2bf(v.y); o.z = f2bf(v.z); o.w = f2bf(v.w);
    ((ushort4*)out)[i] = o;
}

// W[h][c][d] (16,1024,64) -> out[(h*64+d)*1024 + c] bf16, LDS transpose tile.
__global__ void k_headT(const float* __restrict__ W, unsigned short* __restrict__ out) {
    __shared__ float tile[64][65];
    const int tid = threadIdx.x;
    const int c0 = blockIdx.x * 64, h = blockIdx.y;
    const float* src = W + ((long)h << 16) + (long)c0 * 64;
    #pragma unroll
    for (int j = 0; j < 16; ++j) {
        int idx = j * 256 + tid;
        tile[idx >> 6][idx & 63] = src[idx];
    }
    __syncthreads();
    #pragma unroll
    for (int j = 0; j < 16; ++j) {
        int idx = j * 256 + tid;
        int d = idx >> 6, c = idx & 63;
        out[(long)(h * 64 + d) * 1024 + c0 + c] = f2bf(tile[c][d]);
    }
}

// ---------------- LayerNorm over T axis ----------------
__global__ void k_ln_part(const float* __restrict__ x, float* __restrict__ psum, float* __restrict__ psq) {
    int c = blockIdx.x * BDIM + threadIdx.x;
    int tc = blockIdx.y, b = blockIdx.z;
    const float* p = x + ((long)b << 20) + ((long)tc * 128) * 1024 + c;
    float s = 0.f, ss = 0.f;
    for (int t = 0; t < 128; ++t) {
        float v = p[t * 1024];
        s += v; ss += v * v;
    }
    int o = (b * 8 + tc) * 1024 + c;
    psum[o] = s; psq[o] = ss;
}

__global__ void k_ln_fin(const float* __restrict__ psum, const float* __restrict__ psq,
                         float* __restrict__ mean, float* __restrict__ rstd) {
    int i = blockIdx.x * BDIM + threadIdx.x;  // 4096 = B*C
    int b = i >> 10, c = i & 1023;
    float s = 0.f, ss = 0.f;
    for (int j = 0; j < 8; ++j) {
        s  += psum[(b * 8 + j) * 1024 + c];
        ss += psq[(b * 8 + j) * 1024 + c];
    }
    float m = s * (1.0f / 1024.0f);
    float var = (ss - 1024.0f * m * m) * (1.0f / 1023.0f);   // ddof=1
    mean[i] = m;
    rstd[i] = rsqrtf(var + 1e-5f);
}

__global__ void k_ln_apply(const float* __restrict__ x, const float* __restrict__ mean,
                           const float* __restrict__ rstd, const float* __restrict__ g,
                           const float* __restrict__ beta, unsigned short* __restrict__ out) {
    int i = blockIdx.x * BDIM + threadIdx.x;   // 1M, 4 elems each
    int flat = i << 2;
    int b = flat >> 20, c = flat & 1023;
    float4 xv = ((const float4*)x)[i];
    float4 mv = *(const float4*)&mean[(b << 10) + c];
    float4 rv = *(const float4*)&rstd[(b << 10) + c];
    float4 gv = *(const float4*)&g[c];
    float4 bv = *(const float4*)&beta[c];
    ushort4 o;
    o.x = f2bf(gv.x * (xv.x - mv.x) * rv.x + bv.x);
    o.y = f2bf(gv.y * (xv.y - mv.y) * rv.y + bv.y);
    o.z = f2bf(gv.z * (xv.z - mv.z) * rv.z + bv.z);
    o.w = f2bf(gv.w * (xv.w - mv.w) * rv.w + bv.w);
    ((ushort4*)out)[i] = o;
}

// prefill for split-K FF2: out[i] = res[i] + bias[col]
__global__ void k_addbias(const float* __restrict__ res, const float* __restrict__ bias,
                          float* __restrict__ out) {
    int i = blockIdx.x * BDIM + threadIdx.x;   // 1M float4
    int c = (i << 2) & 1023;
    float4 r = ((const float4*)res)[i];
    float4 bv = *(const float4*)&bias[c];
    r.x += bv.x; r.y += bv.y; r.z += bv.z; r.w += bv.w;
    ((float4*)out)[i] = r;
}

// ---------------- 128x128 BT GEMM, BK=64, 2 blocks/CU ----------------
// C[i,j] = sum_k A[i,k]*B[j,k]. T3-minimum loop: STAGE(t+1) first, two
// ks-chunks {8 ds_read_b128, lgkmcnt(0), setprio, 16 MFMA} gated per-wave,
// ONE vmcnt(0)+barrier per tile. 64KB LDS + lb(256,2) -> 2 blocks/CU so
// barrier drains of one block hide under the other block's compute (m114).
// LDS swizzle: slot s of row r holds k-block s ^ ((r>>1)&7) (0-conflict
// pattern, PMC-verified rounds 5-8). Staging lane-linear dest, source
// k-block pre-swizzled.
// EPI: 0 = bf16 out; 1 = f32 + bias[col] + res; 2 = bf16 relu(v+bias);
//      3 = f32 atomicAdd (split-K via blockIdx.z with sA/sB as k-offset).
template <int EPI>
__global__ __launch_bounds__(256, 2) void k_gemm_bt(
    const unsigned short* __restrict__ A, const unsigned short* __restrict__ B,
    void* __restrict__ Cv, const float* __restrict__ bias, const float* __restrict__ res,
    int N, int K, int ldA, int ldB, long sA, long sB, long sC)
{
    __shared__ __align__(16) unsigned short As[2][128 * 64];
    __shared__ __align__(16) unsigned short Bs[2][128 * 64];
    const int tid = threadIdx.x;
    const int wv = tid >> 6, l = tid & 63;
    const long bz = blockIdx.z;

    // XCD-bijective swizzle (nwg % 8 == 0 for all our grids)
    const int gx = gridDim.x;
    const int nwg = gx * gridDim.y;
    int lin = blockIdx.y * gx + blockIdx.x;
    lin = (lin & 7) * (nwg >> 3) + (lin >> 3);
    const int m0 = (lin / gx) * 128, n0 = (lin % gx) * 128;

    const int lr = l & 15, lg = l >> 4;

    // staging: wave wv, issue L(0..3): row = wv*32 + L*8 + (l>>3), slot l&7;
    // fetch k-block g = (l&7) ^ ((L*4 + (l>>4)) & 7)  [slot^((row>>1)&7)]
    const int srow = wv * 32 + (l >> 3);
    const unsigned short* pA = A + bz * sA + (long)(m0 + srow) * ldA;
    const unsigned short* pB = B + bz * sB + (long)(n0 + srow) * ldB;

    auto stage = [&](int k0, int d) {
        #pragma unroll
        for (int L = 0; L < 4; ++L) {
            const int g = ((l & 7) ^ ((L * 4 + (l >> 4)) & 7)) * 8;
            gload_lds16(pA + (long)(L * 8) * ldA + k0 + g, &As[d][(wv * 4 + L) * 512]);
            gload_lds16(pB + (long)(L * 8) * ldB + k0 + g, &Bs[d][(wv * 4 + L) * 512]);
        }
    };

    f32x4 acc[4][4] = {};
    const int wm = (wv >> 1) * 64, wn = (wv & 1) * 64;
    const int rsw = (lr >> 1) & 7;

    const int nt = K >> 6;
    stage(0, 0);
    asm volatile("s_waitcnt vmcnt(0)" ::: "memory");
    __builtin_amdgcn_s_barrier();
    __builtin_amdgcn_sched_barrier(0);

    for (int t = 0; t < nt; ++t) {
        const int d = t & 1;
        if (t + 1 < nt) stage((t + 1) << 6, d ^ 1);   // issue before compute
        #pragma unroll
        for (int ks = 0; ks < 2; ++ks) {
            bf16x8 af[4], bfr[4];
            #pragma unroll
            for (int fm = 0; fm < 4; ++fm)
                af[fm] = *(const bf16x8*)&As[d][(wm + fm * 16 + lr) * 64 + (((ks * 4 + lg) ^ rsw) * 8)];
            #pragma unroll
            for (int fn = 0; fn < 4; ++fn)
                bfr[fn] = *(const bf16x8*)&Bs[d][(wn + fn * 16 + lr) * 64 + (((ks * 4 + lg) ^ rsw) * 8)];
            asm volatile("s_waitcnt lgkmcnt(0)" ::: "memory");
            __builtin_amdgcn_sched_barrier(0);        // rule #18
            __builtin_amdgcn_s_setprio(1);
            #pragma unroll
            for (int fm = 0; fm < 4; ++fm)
                #pragma unroll
                for (int fn = 0; fn < 4; ++fn)
                    acc[fm][fn] = __builtin_amdgcn_mfma_f32_16x16x32_bf16(af[fm], bfr[fn], acc[fm][fn], 0, 0, 0);
            __builtin_amdgcn_s_setprio(0);
            __builtin_amdgcn_sched_barrier(0);
        }
        asm volatile("s_waitcnt vmcnt(0)" ::: "memory");   // stage(t+1) landed
        __builtin_amdgcn_s_barrier();                      // reads of buf d done
        __builtin_amdgcn_sched_barrier(0);
    }

    const int cr0 = lg * 4;
    #pragma unroll
    for (int fm = 0; fm < 4; ++fm) {
        #pragma unroll
        for (int r = 0; r < 4; ++r) {
            const int row = m0 + wm + fm * 16 + cr0 + r;
            const long rb = bz * sC + (long)row * N;
            #pragma unroll
            for (int fn = 0; fn < 4; ++fn) {
                const int col = n0 + wn + fn * 16 + lr;
                float v = acc[fm][fn][r];
                if (EPI == 0) {
                    ((unsigned short*)Cv)[rb + col] = f2bf(v);
                } else if (EPI == 1) {
                    ((float*)Cv)[rb + col] = v + bias[col] + res[rb + col];
                } else if (EPI == 2) {
                    v += bias[col];
                    ((unsigned short*)Cv)[rb + col] = f2bf(v > 0.f ? v : 0.f);
                } else {
                    atomicAdd(&((float*)Cv)[rb + col], v);
                }
            }
        }
    }
}

// ---------------- flash attention (causal, q==k tensor) ----------------
#define CEXP 0.18033688f   // 0.125 * log2(e)
#define PSTRIDE 72

__global__ __launch_bounds__(256, 2) void k_attn(
    const unsigned short* __restrict__ qk, const unsigned short* __restrict__ vt,
    unsigned short* __restrict__ ctx)
{
    __shared__ __align__(16) unsigned short Ks[64 * 64];
    __shared__ __align__(16) unsigned short Vs[64 * 64];
    __shared__ __align__(16) unsigned short P[4][16 * PSTRIDE];
    const int tid = threadIdx.x;
    const int wave = tid >> 6, lane = tid & 63;
    const int bh = blockIdx.x >> 3, pairIdx = blockIdx.x & 7;
    const int b = bh >> 4, h = bh & 15;
    const int lr = lane & 15, lg = lane >> 4;

    const int swz = (lr & 7) << 4;
    const int cby0 = (lg * 16) ^ swz;
    const int cby1 = (64 + lg * 16) ^ swz;
    const int srow_l = lane >> 3;
    const int scol = ((lane & 7) * 8) ^ (srow_l << 3);   // u16 units

    unsigned short* Pw = P[wave];
    char* KsB = (char*)Ks;
    char* VsB = (char*)Vs;
    const unsigned short* qbase = qk + ((long)b << 20) + h * 64;
    const unsigned short* vb    = vt + ((long)(b * 16 + h) << 16);

    #pragma unroll 1
    for (int phase = 0; phase < 2; ++phase) {
        const int qb = phase ? (15 - pairIdx) : pairIdx;
        const int q0 = qb << 6;
        const int qw = q0 + wave * 16;

        const unsigned short* qrow = qbase + (long)(qw + lr) * 1024 + lg * 8;
        const bf16x8 aq0 = *(const bf16x8*)qrow;
        const bf16x8 aq1 = *(const bf16x8*)(qrow + 32);

        f32x4 acc[4] = {};
        float mrow[4] = {-1e30f, -1e30f, -1e30f, -1e30f};
        float lrow[4] = {0.f, 0.f, 0.f, 0.f};

        for (int c = 0; c <= qb; ++c) {
            const int k0 = c << 6;
            __syncthreads();
            #pragma unroll
            for (int i = 0; i < 2; ++i) {
                const int row = i * 32 + wave * 8 + srow_l;
                gload_lds16(qbase + (long)(k0 + row) * 1024 + scol,
                            KsB + i * 4096 + wave * 1024);
                gload_lds16(vb + (long)row * 1024 + k0 + scol,
                            VsB + i * 4096 + wave * 1024);
            }
            __syncthreads();

            f32x4 s[4];
            #pragma unroll
            for (int t = 0; t < 4; ++t) {
                const int r = t * 16 + lr;
                bf16x8 bk0 = *(const bf16x8*)(KsB + r * 128 + cby0);
                bf16x8 bk1 = *(const bf16x8*)(KsB + r * 128 + cby1);
                f32x4 z = {};
                z = __builtin_amdgcn_mfma_f32_16x16x32_bf16(aq0, bk0, z, 0, 0, 0);
                s[t] = __builtin_amdgcn_mfma_f32_16x16x32_bf16(aq1, bk1, z, 0, 0, 0);
            }
            if (c == qb) {
                #pragma unroll
                for (int t = 0; t < 4; ++t) {
                    const int col = t * 16 + lr;
                    #pragma unroll
                    for (int r = 0; r < 4; ++r)
                        if (col > wave * 16 + lg * 4 + r) s[t][r] = -1e30f;
                }
            }
            float fac[4];
            #pragma unroll
            for (int r = 0; r < 4; ++r) {
                float v = fmaxf(fmaxf(s[0][r], s[1][r]), fmaxf(s[2][r], s[3][r]));
                v = fmaxf(v, __shfl_xor(v, 1));
                v = fmaxf(v, __shfl_xor(v, 2));
                v = fmaxf(v, __shfl_xor(v, 4));
                v = fmaxf(v, __shfl_xor(v, 8));
                float mn = fmaxf(mrow[r], v);
                fac[r] = exp2f((mrow[r] - mn) * CEXP);
                mrow[r] = mn;
            }
            float psum[4] = {0.f, 0.f, 0.f, 0.f};
            #pragma unroll
            for (int t = 0; t < 4; ++t) {
                #pragma unroll
                for (int r = 0; r < 4; ++r) {
                    float p = exp2f((s[t][r] - mrow[r]) * CEXP);
                    psum[r] += p;
                    Pw[(lg * 4 + r) * PSTRIDE + t * 16 + lr] = f2bf(p);
                }
            }
            #pragma unroll
            for (int r = 0; r < 4; ++r) {
                float v = psum[r];
                v += __shfl_xor(v, 1); v += __shfl_xor(v, 2);
                v += __shfl_xor(v, 4); v += __shfl_xor(v, 8);
                lrow[r] = lrow[r] * fac[r] + v;
            }
            #pragma unroll
            for (int ni = 0; ni < 4; ++ni)
                #pragma unroll
                for (int r = 0; r < 4; ++r)
                    acc[ni][r] *= fac[r];
            const bf16x8 pa0 = *(const bf16x8*)&Pw[lr * PSTRIDE + lg * 8];
            const bf16x8 pa1 = *(const bf16x8*)&Pw[lr * PSTRIDE + 32 + lg * 8];
            #pragma unroll
            for (int ni = 0; ni < 4; ++ni) {
                const int vr = ni * 16 + lr;
                bf16x8 bv0 = *(const bf16x8*)(VsB + vr * 128 + cby0);
                bf16x8 bv1 = *(const bf16x8*)(VsB + vr * 128 + cby1);
                acc[ni] = __builtin_amdgcn_mfma_f32_16x16x32_bf16(pa0, bv0, acc[ni], 0, 0, 0);
                acc[ni] = __builtin_amdgcn_mfma_f32_16x16x32_bf16(pa1, bv1, acc[ni], 0, 0, 0);
            }
        }

        unsigned short* crow = ctx + ((long)(b * 1024 + qw)) * 1024 + h * 64;
        #pragma unroll
        for (int r = 0; r < 4; ++r) {
            const float inv = 1.0f / lrow[r];
            #pragma unroll
            for (int ni = 0; ni < 4; ++ni)
                crow[(long)(lg * 4 + r) * 1024 + ni * 16 + lr] = f2bf(acc[ni][r] * inv);
        }
    }
}

// ---------------- launcher ----------------
extern "C" void kernel_launch(void* const* d_in, const int* in_sizes, int n_in,
                              void* d_out, int out_size, void* d_ws, size_t ws_size,
                              hipStream_t stream)
{
    const float* x   = (const float*)d_in[0];
    const float* Wk  = (const float*)d_in[1];
    const float* Wv  = (const float*)d_in[2];
    const float* Wp  = (const float*)d_in[3];
    const float* bp  = (const float*)d_in[4];
    const float* W1  = (const float*)d_in[5];
    const float* b1  = (const float*)d_in[6];
    const float* W2  = (const float*)d_in[7];
    const float* b2  = (const float*)d_in[8];
    const float* g1  = (const float*)d_in[9];
    const float* be1 = (const float*)d_in[10];
    const float* g2  = (const float*)d_in[11];
    const float* be2 = (const float*)d_in[12];
    float* out = (float*)d_out;

    char* ws = (char*)d_ws;
    const long MB = 1024 * 1024;
    unsigned short* BkT = (unsigned short*)(ws);
    unsigned short* WvT = (unsigned short*)(ws + 2 * MB);
    unsigned short* WpB = (unsigned short*)(ws + 4 * MB);
    unsigned short* W1B = (unsigned short*)(ws + 6 * MB);
    unsigned short* W2B = (unsigned short*)(ws + 14 * MB);
    unsigned short* hB  = (unsigned short*)(ws + 22 * MB);
    unsigned short* qkB = (unsigned short*)(ws + 30 * MB);
    unsigned short* VtB = (unsigned short*)(ws + 38 * MB);
    unsigned short* ctx = (unsigned short*)(ws + 46 * MB);
    unsigned short* ff1 = (unsigned short*)(ws + 30 * MB);  // overlays qk/Vt/ctx
    float* x2   = (float*)(ws + 62 * MB);
    float* psum = (float*)(ws + 78 * MB);
    float* psq  = (float*)(ws + 78 * MB + 128 * 1024);
    float* mean = (float*)(ws + 78 * MB + 256 * 1024);
    float* rstd = (float*)(ws + 78 * MB + 272 * 1024);

    // weight prep
    k_cast_bf16<<<1024, BDIM, 0, stream>>>(Wp, WpB, 262144);
    k_cast_bf16<<<4096, BDIM, 0, stream>>>(W1, W1B, 1048576);
    k_cast_bf16<<<4096, BDIM, 0, stream>>>(W2, W2B, 1048576);
    k_headT<<<dim3(16, 16), BDIM, 0, stream>>>(Wk, BkT);
    k_headT<<<dim3(16, 16), BDIM, 0, stream>>>(Wv, WvT);

    // LN1 (over T axis)
    k_ln_part<<<dim3(4, 8, 4), BDIM, 0, stream>>>(x, psum, psq);
    k_ln_fin<<<16, BDIM, 0, stream>>>(psum, psq, mean, rstd);
    k_ln_apply<<<4096, BDIM, 0, stream>>>(x, mean, rstd, g1, be1, hB);

    // projections
    k_gemm_bt<0><<<dim3(8, 32, 1), BDIM, 0, stream>>>(hB, BkT, qkB, nullptr, nullptr, 1024, 1024, 1024, 1024, 0, 0, 0);
    k_gemm_bt<0><<<dim3(8, 8, 4), BDIM, 0, stream>>>(WvT, hB, VtB, nullptr, nullptr, 1024, 1024, 1024, 1024, 0, MB, MB);

    // flash attention -> ctx bf16 [4096, 1024]
    k_attn<<<512, BDIM, 0, stream>>>(qkB, VtB, ctx);

    // out-proj + bias + residual -> x2 f32
    k_gemm_bt<1><<<dim3(8, 32, 1), BDIM, 0, stream>>>(ctx, WpB, x2, bp, x, 1024, 1024, 1024, 1024, 0, 0, 0);

    // LN2
    k_ln_part<<<dim3(4, 8, 4), BDIM, 0, stream>>>(x2, psum, psq);
    k_ln_fin<<<16, BDIM, 0, stream>>>(psum, psq, mean, rstd);
    k_ln_apply<<<4096, BDIM, 0, stream>>>(x2, mean, rstd, g2, be2, hB);

    // FF1: ff1 = relu(h2 @ W1^T + b1) bf16, grid 1024 -> 2 blocks/CU resident
    k_gemm_bt<2><<<dim3(32, 32, 1), BDIM, 0, stream>>>(hB, W1B, ff1, b1, nullptr, 4096, 1024, 1024, 1024, 0, 0, 0);

    // FF2 split-K=2: out = x2 + b2 (prefill), then out += ff1 @ W2^T (atomic)
    k_addbias<<<4096, BDIM, 0, stream>>>(x2, b2, out);
    k_gemm_bt<3><<<dim3(8, 32, 2), BDIM, 0, stream>>>(ff1, W2B, out, nullptr, nullptr, 1024, 2048, 4096, 4096, 2048, 2048, 0);
}